// Round 13
// baseline (261.509 us; speedup 1.0000x reference)
//
#include <hip/hip_runtime.h>
#include <math.h>

#define NB 4
#define NC 64
#define NC8 8
#define NCC 21
#define NHW 4096
#define NHM 128

typedef __attribute__((ext_vector_type(8))) short bf16x8;
typedef __attribute__((ext_vector_type(4))) float f32x4;

__device__ __forceinline__ float gelu_exact(float x) {
    return 0.5f * x * (1.0f + erff(x * 0.70710678118654752f));
}

__device__ __forceinline__ unsigned short f2bf(float x) {
    union { float f; unsigned u; } u; u.f = x;
    unsigned r = u.u + 0x7fffu + ((u.u >> 16) & 1u);   // RNE
    return (unsigned short)(r >> 16);
}

__device__ __forceinline__ float bf2f(unsigned short v) {
    union { unsigned u; float f; } t; t.u = (unsigned)v << 16; return t.f;
}

// ---------------- weight pack/transpose into [ci][co] layouts; zero pool ----------------
// o: [0) qkv 5120 | [5120) cab1 12096 | [17216) cab2 12096 | [29312) proj 4096
//    [33408) fc1 8192 | [41600) fc2 8192
__global__ void k_wt(const float* __restrict__ qw, const float* __restrict__ kw,
                     const float* __restrict__ vw, const float* __restrict__ c1w,
                     const float* __restrict__ c2w, const float* __restrict__ pw,
                     const float* __restrict__ f1w, const float* __restrict__ f2w,
                     float* __restrict__ o, float* __restrict__ pool) {
    int idx = blockIdx.x * 256 + threadIdx.x;
    if (idx < 256) pool[idx] = 0.f;
    if (idx < 5120) {
        int ci = idx / 80, j = idx - ci * 80;
        float v = j < 8 ? qw[j * 64 + ci] : (j < 16 ? kw[(j - 8) * 64 + ci] : vw[(j - 16) * 64 + ci]);
        o[idx] = v;
    } else if (idx < 17216) {
        int r = idx - 5120; int co = r % 21, q = r / 21; int ci = q / 9, t = q - ci * 9;
        o[idx] = c1w[co * 576 + ci * 9 + t];
    } else if (idx < 29312) {
        int r = idx - 17216; int co = r & 63, q = r >> 6; int ci = q / 9, t = q - ci * 9;
        o[idx] = c2w[co * 189 + ci * 9 + t];
    } else if (idx < 33408) {
        int r = idx - 29312; int co = r & 63, ci = r >> 6;
        o[idx] = pw[co * 64 + ci];
    } else if (idx < 41600) {
        int r = idx - 33408; int m = r & 127, c = r >> 7;
        o[idx] = f1w[m * 64 + c];
    } else if (idx < 49792) {
        int r = idx - 41600; int wo = r & 63, m = r >> 6;
        o[idx] = f2w[wo * 128 + m];
    }
}

// ---------------- LayerNorm over channel dim; 4 threads per pixel; bf16 out ----------------
__global__ __launch_bounds__(256) void k_ln(const float* __restrict__ in, const float* __restrict__ w,
                                            const float* __restrict__ bb, unsigned short* __restrict__ out) {
    __shared__ float r1[4][64], r2[4][64];
    int tid = threadIdx.x;
    int pl = tid & 63, cq = tid >> 6;
    int b = blockIdx.x >> 6;
    int pix = (blockIdx.x & 63) * 64 + pl;
    const float* p = in + (size_t)b * NC * NHW + pix;
    float v[16]; float s = 0.f, ss = 0.f;
    #pragma unroll
    for (int k = 0; k < 16; ++k) {
        float f = p[(size_t)(cq * 16 + k) * NHW];
        v[k] = f; s += f; ss += f * f;
    }
    r1[cq][pl] = s; r2[cq][pl] = ss;
    __syncthreads();
    float S  = r1[0][pl] + r1[1][pl] + r1[2][pl] + r1[3][pl];
    float SS = r2[0][pl] + r2[1][pl] + r2[2][pl] + r2[3][pl];
    float mean = S * (1.0f / 64);
    float rstd = rsqrtf(SS * (1.0f / 64) - mean * mean + 1e-5f);
    unsigned short* q = out + (size_t)b * NC * NHW + pix;
    #pragma unroll
    for (int k = 0; k < 16; ++k) {
        int c = cq * 16 + k;
        q[(size_t)c * NHW] = f2bf((v[k] - mean) * rstd * w[c] + bb[c]);
    }
}

// ---------------- q/k/v 1x1 convs: bf16 in/out, LDS weights, 2 pixels/thread, G=10 x 8 ----------------
__global__ __launch_bounds__(256) void k_qkv(const unsigned short* __restrict__ xn,
        const float* __restrict__ wt, const float* __restrict__ qb,
        const float* __restrict__ kb, const float* __restrict__ vb,
        unsigned short* __restrict__ q1, unsigned short* __restrict__ k1,
        unsigned short* __restrict__ v1) {
    __shared__ float wl[64][12];
    int tid = threadIdx.x;
    int co0 = blockIdx.y * 10, b = blockIdx.z;
    for (int idx = tid; idx < 192; idx += 256) {
        int ci = idx / 3, j4 = idx % 3;
        float4 t;
        t.x = (j4 * 4 + 0 < 10) ? wt[ci * 80 + co0 + j4 * 4 + 0] : 0.f;
        t.y = (j4 * 4 + 1 < 10) ? wt[ci * 80 + co0 + j4 * 4 + 1] : 0.f;
        t.z = (j4 * 4 + 2 < 10) ? wt[ci * 80 + co0 + j4 * 4 + 2] : 0.f;
        t.w = (j4 * 4 + 3 < 10) ? wt[ci * 80 + co0 + j4 * 4 + 3] : 0.f;
        *(float4*)&wl[ci][j4 * 4] = t;
    }
    __syncthreads();
    int pix = (blockIdx.x * 256 + tid) * 2;
    float a0[10], a1[10];
    #pragma unroll
    for (int j = 0; j < 10; ++j) { a0[j] = 0.f; a1[j] = 0.f; }
    const unsigned short* p = xn + (size_t)b * NC * NHW + pix;
    for (int ci = 0; ci < NC; ++ci) {
        ushort2 uv = *(const ushort2*)(p + (size_t)ci * NHW);
        float fx = bf2f(uv.x), fy = bf2f(uv.y);
        float wv[12];
        *(float4*)&wv[0] = *(const float4*)&wl[ci][0];
        *(float4*)&wv[4] = *(const float4*)&wl[ci][4];
        *(float4*)&wv[8] = *(const float4*)&wl[ci][8];
        #pragma unroll
        for (int j = 0; j < 10; ++j) {
            a0[j] = fmaf(fx, wv[j], a0[j]);
            a1[j] = fmaf(fy, wv[j], a1[j]);
        }
    }
    #pragma unroll
    for (int j = 0; j < 10; ++j) {
        int co = co0 + j;
        float bsv; unsigned short* dst;
        if (co < 8)       { bsv = qb[co];      dst = q1 + ((size_t)b * NC8 + co) * NHW + pix; }
        else if (co < 16) { bsv = kb[co - 8];  dst = k1 + ((size_t)b * NC8 + co - 8) * NHW + pix; }
        else              { bsv = vb[co - 16]; dst = v1 + ((size_t)b * NC + co - 16) * NHW + pix; }
        ushort2 o = { f2bf(a0[j] + bsv), f2bf(a1[j] + bsv) };
        *(ushort2*)dst = o;
    }
}

// ---------------- depthwise 3x3, q+k merged: bf16 in, bf16 out, (b,pix,8) layout ----------------
__global__ void k_dw3x3_qk(const unsigned short* __restrict__ q1, const unsigned short* __restrict__ k1,
                           const float* __restrict__ w, const float* __restrict__ bias,
                           unsigned short* __restrict__ qdb, unsigned short* __restrict__ kdb) {
    int pix = blockIdx.x * blockDim.x + threadIdx.x;
    int cy = blockIdx.y, b = blockIdx.z;
    int c = cy & 7;
    const unsigned short* ip = (cy < 8 ? q1 : k1) + ((size_t)b * NC8 + c) * NHW;
    unsigned short* outT = (cy < 8 ? qdb : kdb);
    int y = pix >> 6, x = pix & 63;
    const float* wp = w + c * 9;
    float acc = bias[c];
    #pragma unroll
    for (int dy = -1; dy <= 1; ++dy) {
        int yy = y + dy; if (yy < 0 || yy > 63) continue;
        #pragma unroll
        for (int dx = -1; dx <= 1; ++dx) {
            int xx = x + dx; if (xx < 0 || xx > 63) continue;
            acc += wp[(dy + 1) * 3 + (dx + 1)] * bf2f(ip[yy * 64 + xx]);
        }
    }
    outT[((size_t)b * NHW + pix) * NC8 + c] = f2bf(acc);
}

// ---------------- depthwise 3x3, v path: bf16 in/out, chunked layout V8[b][pix>>3][c][pix&7] ----------------
__global__ void k_dw3x3_v(const unsigned short* __restrict__ in, const float* __restrict__ w,
                          const float* __restrict__ bias, unsigned short* __restrict__ v8) {
    int pix = blockIdx.x * blockDim.x + threadIdx.x;
    int c = blockIdx.y, b = blockIdx.z;
    int y = pix >> 6, x = pix & 63;
    const unsigned short* ip = in + ((size_t)b * NC + c) * NHW;
    const float* wp = w + c * 9;
    float acc = bias[c];
    #pragma unroll
    for (int dy = -1; dy <= 1; ++dy) {
        int yy = y + dy; if (yy < 0 || yy > 63) continue;
        #pragma unroll
        for (int dx = -1; dx <= 1; ++dx) {
            int xx = x + dx; if (xx < 0 || xx > 63) continue;
            acc += wp[(dy + 1) * 3 + (dx + 1)] * bf2f(ip[yy * 64 + xx]);
        }
    }
    v8[(((size_t)b * 512 + (pix >> 3)) * NC + c) * 8 + (pix & 7)] = f2bf(acc);
}

// ---------------- flash attention: 8 waves/block, i-tile x2 in-wave, chunked-V, LDS union ----------------
// Block = 8 waves (512 thr), one 32-row i-tile (two 16-row strips sharing K/V loads);
// wave w owns j in [w*512,(w+1)*512). Per-wave LDS P reused sequentially per strip.
// Ocmb partials stored bf16 so the P/Ocmb union stays 35.8 KB (4 blocks/CU LDS bound).
__global__ __launch_bounds__(512) void k_flash(const unsigned short* __restrict__ qdb,
                                               const unsigned short* __restrict__ kdb,
                                               const unsigned short* __restrict__ v8,
                                               unsigned short* __restrict__ O) {
    __shared__ __align__(16) char smem[35840];  // max(Pl 8*2304=18432, Ocmb 16*1088*2=34816 + Lw 1024)
    int tid = threadIdx.x;
    int w = tid >> 6, lane = tid & 63;
    int g = lane >> 4, il = lane & 15;
    int i0 = blockIdx.x * 32, b = blockIdx.y;

    unsigned short (*P)[72] = (unsigned short (*)[72])(smem + w * 2304);

    bf16x8 qb0 = (bf16x8)(short)0, qb1 = (bf16x8)(short)0;
    if (g == 0) {
        qb0 = *(const bf16x8*)(qdb + (size_t)(b * NHW + i0 + il) * NC8);
        qb1 = *(const bf16x8*)(qdb + (size_t)(b * NHW + i0 + 16 + il) * NC8);
    }

    f32x4 acc0[4], acc1[4];
    #pragma unroll
    for (int ct = 0; ct < 4; ++ct) {
        acc0[ct] = (f32x4){0.f, 0.f, 0.f, 0.f};
        acc1[ct] = (f32x4){0.f, 0.f, 0.f, 0.f};
    }
    float La0 = 0.f, La1 = 0.f;

    bf16x8 kn[4];
    #pragma unroll
    for (int t = 0; t < 4; ++t) {
        kn[t] = (bf16x8)(short)0;
        if (g == 0) kn[t] = *(const bf16x8*)(kdb + (size_t)(b * NHW + w * 512 + 16 * t + il) * NC8);
    }

    for (int jt = 0; jt < 8; ++jt) {
        int j0 = w * 512 + jt * 64;
        int ch0 = b * 512 + (j0 >> 3);
        bf16x8 va[2][4];
        #pragma unroll
        for (int kc = 0; kc < 2; ++kc)
            #pragma unroll
            for (int ct = 0; ct < 4; ++ct)
                va[kc][ct] = *(const bf16x8*)(v8 +
                    ((size_t)(ch0 + kc * 4 + g) * NC + ct * 16 + il) * 8);
        bf16x8 ka[4];
        #pragma unroll
        for (int t = 0; t < 4; ++t) ka[t] = kn[t];
        if (jt < 7) {
            #pragma unroll
            for (int t = 0; t < 4; ++t) {
                kn[t] = (bf16x8)(short)0;
                if (g == 0) kn[t] = *(const bf16x8*)(kdb + (size_t)(b * NHW + j0 + 64 + 16 * t + il) * NC8);
            }
        }
        // ---- strip 0 ----
        #pragma unroll
        for (int t = 0; t < 4; ++t) {
            f32x4 sv = __builtin_amdgcn_mfma_f32_16x16x32_bf16(ka[t], qb0, (f32x4){0.f, 0.f, 0.f, 0.f}, 0, 0, 0);
            float p0 = __expf(sv[0]), p1 = __expf(sv[1]);
            float p2 = __expf(sv[2]), p3 = __expf(sv[3]);
            La0 += (p0 + p1) + (p2 + p3);
            ushort4 pk;
            pk.x = f2bf(p0); pk.y = f2bf(p1); pk.z = f2bf(p2); pk.w = f2bf(p3);
            *(ushort4*)&P[il][16 * t + 4 * g] = pk;
        }
        #pragma unroll
        for (int kc = 0; kc < 2; ++kc) {
            bf16x8 pb = *(const bf16x8*)&P[il][kc * 32 + 8 * g];
            #pragma unroll
            for (int ct = 0; ct < 4; ++ct)
                acc0[ct] = __builtin_amdgcn_mfma_f32_16x16x32_bf16(va[kc][ct], pb, acc0[ct], 0, 0, 0);
        }
        // ---- strip 1 (reuse P, same ka/va) ----
        #pragma unroll
        for (int t = 0; t < 4; ++t) {
            f32x4 sv = __builtin_amdgcn_mfma_f32_16x16x32_bf16(ka[t], qb1, (f32x4){0.f, 0.f, 0.f, 0.f}, 0, 0, 0);
            float p0 = __expf(sv[0]), p1 = __expf(sv[1]);
            float p2 = __expf(sv[2]), p3 = __expf(sv[3]);
            La1 += (p0 + p1) + (p2 + p3);
            ushort4 pk;
            pk.x = f2bf(p0); pk.y = f2bf(p1); pk.z = f2bf(p2); pk.w = f2bf(p3);
            *(ushort4*)&P[il][16 * t + 4 * g] = pk;
        }
        #pragma unroll
        for (int kc = 0; kc < 2; ++kc) {
            bf16x8 pb = *(const bf16x8*)&P[il][kc * 32 + 8 * g];
            #pragma unroll
            for (int ct = 0; ct < 4; ++ct)
                acc1[ct] = __builtin_amdgcn_mfma_f32_16x16x32_bf16(va[kc][ct], pb, acc1[ct], 0, 0, 0);
        }
    }
    La0 += __shfl_xor(La0, 16, 64); La0 += __shfl_xor(La0, 32, 64);
    La1 += __shfl_xor(La1, 16, 64); La1 += __shfl_xor(La1, 32, 64);

    __syncthreads();   // all waves done with P before Ocmb overlays it
    unsigned short* Ocm = (unsigned short*)smem;           // [16][64*17] bf16 (waveslot = w*2+strip)
    float* Lw = (float*)(smem + 34816);                    // [16][16]
    #pragma unroll
    for (int ct = 0; ct < 4; ++ct)
        #pragma unroll
        for (int e = 0; e < 4; ++e) {
            int c = ct * 16 + 4 * g + e;
            Ocm[(w * 2 + 0) * 1088 + c * 17 + il] = f2bf(acc0[ct][e]);
            Ocm[(w * 2 + 1) * 1088 + c * 17 + il] = f2bf(acc1[ct][e]);
        }
    if (lane < 16) {
        Lw[(w * 2 + 0) * 16 + il] = La0;
        Lw[(w * 2 + 1) * 16 + il] = La1;
    }
    __syncthreads();

    int st = tid >> 8, rem = tid & 255;    // strip, then 16 i x 16 ch
    int ic = rem & 15, ch = rem >> 4;
    float l = 0.f;
    #pragma unroll
    for (int w2 = 0; w2 < 8; ++w2) l += Lw[(w2 * 2 + st) * 16 + ic];
    float rl = 1.0f / l;
    #pragma unroll
    for (int cc = 0; cc < 4; ++cc) {
        int c = cc * 16 + ch;
        float o = 0.f;
        #pragma unroll
        for (int w2 = 0; w2 < 8; ++w2) o += bf2f(Ocm[(w2 * 2 + st) * 1088 + c * 17 + ic]);
        O[(size_t)(b * NC + c) * NHW + i0 + st * 16 + ic] = f2bf(o * rl);
    }
}

// ---------------- CAB conv1 3x3 (64->21), bf16 in, K-split x8, LDS weights, 2 pix ----------------
__global__ __launch_bounds__(256) void k_cab1_p(const unsigned short* __restrict__ xn,
        const float* __restrict__ wt, float* __restrict__ part) {
    __shared__ float wl[72][24];
    int tid = threadIdx.x;
    int s = blockIdx.y, b = blockIdx.z;
    for (int idx = tid; idx < 432; idx += 256) {
        int lt = idx / 6, j4 = idx % 6;
        int ci = s * 8 + lt / 9, t = lt % 9;
        float4 v;
        v.x = (j4 * 4 + 0 < 21) ? wt[(ci * 9 + t) * 21 + j4 * 4 + 0] : 0.f;
        v.y = (j4 * 4 + 1 < 21) ? wt[(ci * 9 + t) * 21 + j4 * 4 + 1] : 0.f;
        v.z = (j4 * 4 + 2 < 21) ? wt[(ci * 9 + t) * 21 + j4 * 4 + 2] : 0.f;
        v.w = (j4 * 4 + 3 < 21) ? wt[(ci * 9 + t) * 21 + j4 * 4 + 3] : 0.f;
        *(float4*)&wl[lt][j4 * 4] = v;
    }
    __syncthreads();
    int pix = (blockIdx.x * 256 + tid) * 2;
    int y = pix >> 6, x0 = pix & 63;
    float a0[21], a1[21];
    #pragma unroll
    for (int co = 0; co < 21; ++co) { a0[co] = 0.f; a1[co] = 0.f; }
    const unsigned short* ip0 = xn + (size_t)b * NC * NHW;
    for (int cc = 0; cc < 8; ++cc) {
        const unsigned short* ip = ip0 + (size_t)(s * 8 + cc) * NHW;
        #pragma unroll
        for (int dy = -1; dy <= 1; ++dy) {
            int yy = y + dy;
            bool yok = (unsigned)yy < 64u;
            #pragma unroll
            for (int dx = -1; dx <= 1; ++dx) {
                int xx0 = x0 + dx, xx1 = x0 + 1 + dx;
                float v0 = (yok && (unsigned)xx0 < 64u) ? bf2f(ip[yy * 64 + xx0]) : 0.f;
                float v1 = (yok && (unsigned)xx1 < 64u) ? bf2f(ip[yy * 64 + xx1]) : 0.f;
                const float* wr = wl[cc * 9 + (dy + 1) * 3 + (dx + 1)];
                float wv[24];
                *(float4*)&wv[0]  = *(const float4*)&wr[0];
                *(float4*)&wv[4]  = *(const float4*)&wr[4];
                *(float4*)&wv[8]  = *(const float4*)&wr[8];
                *(float4*)&wv[12] = *(const float4*)&wr[12];
                *(float4*)&wv[16] = *(const float4*)&wr[16];
                *(float4*)&wv[20] = *(const float4*)&wr[20];
                #pragma unroll
                for (int co = 0; co < 21; ++co) {
                    a0[co] = fmaf(v0, wv[co], a0[co]);
                    a1[co] = fmaf(v1, wv[co], a1[co]);
                }
            }
        }
    }
    size_t ob = ((size_t)(s * NB + b) * NCC) * NHW + pix;
    #pragma unroll
    for (int co = 0; co < 21; ++co) {
        float2 o = { a0[co], a1[co] };
        *(float2*)&part[ob + (size_t)co * NHW] = o;
    }
}

__global__ void k_cab1_c(const float* __restrict__ part, const float* __restrict__ bias,
                         float* __restrict__ y1) {
    int pix = blockIdx.x * 256 + threadIdx.x;
    int co = blockIdx.y, b = blockIdx.z;
    float s = bias[co];
    #pragma unroll
    for (int sp = 0; sp < 8; ++sp)
        s += part[((size_t)(sp * NB + b) * NCC + co) * NHW + pix];
    y1[((size_t)b * NCC + co) * NHW + pix] = gelu_exact(s);
}

// ---------------- CAB conv2 3x3 (21->64), K-split x7 * co-split x2, LDS weights, 2 pix ----------------
__global__ __launch_bounds__(256) void k_cab2_p(const float* __restrict__ y1,
        const float* __restrict__ wt, float* __restrict__ part) {
    __shared__ float wl[27][32];
    int tid = threadIdx.x;
    int s = blockIdx.y >> 1, co0 = (blockIdx.y & 1) * 32, b = blockIdx.z;
    for (int idx = tid; idx < 216; idx += 256) {
        int lt = idx >> 3, j4 = idx & 7;
        int ci = s * 3 + lt / 9, t = lt % 9;
        *(float4*)&wl[lt][j4 * 4] = *(const float4*)&wt[(ci * 9 + t) * 64 + co0 + j4 * 4];
    }
    __syncthreads();
    int pix = (blockIdx.x * 256 + tid) * 2;
    int y = pix >> 6, x0 = pix & 63;
    float a0[32], a1[32];
    #pragma unroll
    for (int co = 0; co < 32; ++co) { a0[co] = 0.f; a1[co] = 0.f; }
    const float* ip0 = y1 + (size_t)b * NCC * NHW;
    for (int cc = 0; cc < 3; ++cc) {
        const float* ip = ip0 + (size_t)(s * 3 + cc) * NHW;
        #pragma unroll
        for (int dy = -1; dy <= 1; ++dy) {
            int yy = y + dy;
            bool yok = (unsigned)yy < 64u;
            #pragma unroll
            for (int dx = -1; dx <= 1; ++dx) {
                int xx0 = x0 + dx, xx1 = x0 + 1 + dx;
                float v0 = (yok && (unsigned)xx0 < 64u) ? ip[yy * 64 + xx0] : 0.f;
                float v1 = (yok && (unsigned)xx1 < 64u) ? ip[yy * 64 + xx1] : 0.f;
                const float* wr = wl[cc * 9 + (dy + 1) * 3 + (dx + 1)];
                float wv[32];
                #pragma unroll
                for (int h = 0; h < 8; ++h)
                    *(float4*)&wv[h * 4] = *(const float4*)&wr[h * 4];
                #pragma unroll
                for (int co = 0; co < 32; ++co) {
                    a0[co] = fmaf(v0, wv[co], a0[co]);
                    a1[co] = fmaf(v1, wv[co], a1[co]);
                }
            }
        }
    }
    size_t ob = ((size_t)(s * NB + b) * NC + co0) * NHW + pix;
    #pragma unroll
    for (int co = 0; co < 32; ++co) {
        float2 o = { a0[co], a1[co] };
        *(float2*)&part[ob + (size_t)co * NHW] = o;
    }
}

// ---------------- combine cab2 partials + fused global-avg-pool (atomic into zeroed pool) ----------------
__global__ void k_cab2_c(const float* __restrict__ part, const float* __restrict__ bias,
                         float* __restrict__ yc, float* __restrict__ pool) {
    __shared__ float red[256];
    int tid = threadIdx.x;
    int pix = blockIdx.x * 256 + tid;
    int co = blockIdx.y, b = blockIdx.z;
    float s = bias[co];
    #pragma unroll
    for (int sp = 0; sp < 7; ++sp)
        s += part[((size_t)(sp * NB + b) * NC + co) * NHW + pix];
    yc[((size_t)b * NC + co) * NHW + pix] = s;
    red[tid] = s;
    __syncthreads();
    for (int st = 128; st > 0; st >>= 1) {
        if (tid < st) red[tid] += red[tid + st];
        __syncthreads();
    }
    if (tid == 0) atomicAdd(&pool[b * NC + co], red[0]);
}

// ---------------- proj 1x1 (G=8) + gamma + xn + inline-CA + shortcut -> fsum ----------------
__global__ __launch_bounds__(256) void k_fsum2(const unsigned short* __restrict__ O,
        const float* __restrict__ pwt, const float* __restrict__ pb,
        const float* __restrict__ gamma, const unsigned short* __restrict__ xn,
        const float* __restrict__ yc, const float* __restrict__ pool,
        const float* __restrict__ cw1, const float* __restrict__ cb1,
        const float* __restrict__ cw2, const float* __restrict__ cb2,
        const float* __restrict__ x, float* __restrict__ fsum) {
    __shared__ float wl[64][8];
    int tid = threadIdx.x;
    int co0 = blockIdx.y * 8, b = blockIdx.z;
    for (int idx = tid; idx < 128; idx += 256) {
        int ci = idx >> 1, h = idx & 1;
        *(float4*)&wl[ci][h * 4] = *(const float4*)&pwt[ci * 64 + co0 + h * 4];
    }
    __syncthreads();
    // inline channel-attention; pool holds SUMS (scale by 1/NHW)
    float h0 = cb1[0], h1 = cb1[1];
    for (int ci = 0; ci < NC; ++ci) {
        float pv = pool[b * NC + ci] * (1.0f / NHW);
        h0 += cw1[ci] * pv;
        h1 += cw1[NC + ci] * pv;
    }
    h0 = fmaxf(h0, 0.f); h1 = fmaxf(h1, 0.f);
    float scv[8];
    #pragma unroll
    for (int j = 0; j < 8; ++j) {
        int c = co0 + j;
        float z = cw2[c * 2] * h0 + cw2[c * 2 + 1] * h1 + cb2[c];
        scv[j] = 1.0f / (1.0f + __expf(-z));
    }
    int pix = (blockIdx.x * 256 + tid) * 2;
    float a0[8], a1[8];
    #pragma unroll
    for (int j = 0; j < 8; ++j) { a0[j] = 0.f; a1[j] = 0.f; }
    const unsigned short* p = O + (size_t)b * NC * NHW + pix;
    for (int ci = 0; ci < NC; ++ci) {
        ushort2 uv = *(const ushort2*)(p + (size_t)ci * NHW);
        float ox = bf2f(uv.x), oy = bf2f(uv.y);
        float wv[8];
        *(float4*)&wv[0] = *(const float4*)&wl[ci][0];
        *(float4*)&wv[4] = *(const float4*)&wl[ci][4];
        #pragma unroll
        for (int j = 0; j < 8; ++j) {
            a0[j] = fmaf(ox, wv[j], a0[j]);
            a1[j] = fmaf(oy, wv[j], a1[j]);
        }
    }
    float g = gamma[0];
    size_t base = (size_t)b * NC * NHW + pix;
    #pragma unroll
    for (int j = 0; j < 8; ++j) {
        int c = co0 + j;
        size_t n = base + (size_t)c * NHW;
        float pbv = pb[c];
        ushort2 xnu = *(const ushort2*)&xn[n];
        float2 ycv = *(const float2*)&yc[n];
        float2 xv  = *(const float2*)&x[n];
        float2 o = { g * (a0[j] + pbv) + bf2f(xnu.x) + ycv.x * scv[j] + xv.x,
                     g * (a1[j] + pbv) + bf2f(xnu.y) + ycv.y * scv[j] + xv.y };
        *(float2*)&fsum[n] = o;
    }
}

// ---------------- MLP fc1 + gelu: bf16 in/out, G=8 x 16 groups, LDS weights, 2 pix ----------------
__global__ __launch_bounds__(256) void k_mlp1(const unsigned short* __restrict__ fs1,
        const float* __restrict__ wt, const float* __restrict__ bias,
        unsigned short* __restrict__ h) {
    __shared__ float wl[64][8];
    int tid = threadIdx.x;
    int m0 = blockIdx.y * 8, b = blockIdx.z;
    for (int idx = tid; idx < 128; idx += 256) {
        int c = idx >> 1, hh = idx & 1;
        *(float4*)&wl[c][hh * 4] = *(const float4*)&wt[c * 128 + m0 + hh * 4];
    }
    __syncthreads();
    int pix = (blockIdx.x * 256 + tid) * 2;
    float a0[8], a1[8];
    #pragma unroll
    for (int j = 0; j < 8; ++j) { float bv = bias[m0 + j]; a0[j] = bv; a1[j] = bv; }
    const unsigned short* p = fs1 + (size_t)b * NC * NHW + pix;
    for (int c = 0; c < NC; ++c) {
        ushort2 uv = *(const ushort2*)(p + (size_t)c * NHW);
        float vx = bf2f(uv.x), vy = bf2f(uv.y);
        float wv[8];
        *(float4*)&wv[0] = *(const float4*)&wl[c][0];
        *(float4*)&wv[4] = *(const float4*)&wl[c][4];
        #pragma unroll
        for (int j = 0; j < 8; ++j) {
            a0[j] = fmaf(vx, wv[j], a0[j]);
            a1[j] = fmaf(vy, wv[j], a1[j]);
        }
    }
    unsigned short* hp = h + (size_t)b * NHM * NHW + pix;
    #pragma unroll
    for (int j = 0; j < 8; ++j) {
        ushort2 o = { f2bf(gelu_exact(a0[j])), f2bf(gelu_exact(a1[j])) };
        *(ushort2*)(hp + (size_t)(m0 + j) * NHW) = o;
    }
}

// ---------------- MLP fc2 (G=8) + raw-view permutation + residual; bf16 h in ----------------
__global__ __launch_bounds__(256) void k_mlp2(const unsigned short* __restrict__ h,
        const float* __restrict__ wt, const float* __restrict__ bias,
        const float* __restrict__ fs, float* __restrict__ out) {
    __shared__ float wl[128][8];
    int tid = threadIdx.x;
    int wo0 = blockIdx.y * 8, b = blockIdx.z;
    for (int idx = tid; idx < 256; idx += 256) {
        int m = idx >> 1, hh = idx & 1;
        *(float4*)&wl[m][hh * 4] = *(const float4*)&wt[m * 64 + wo0 + hh * 4];
    }
    __syncthreads();
    int pix = (blockIdx.x * 256 + tid) * 2;
    float a0[8], a1[8];
    #pragma unroll
    for (int j = 0; j < 8; ++j) { float bv = bias[wo0 + j]; a0[j] = bv; a1[j] = bv; }
    const unsigned short* hp = h + (size_t)b * NHM * NHW + pix;
    for (int m = 0; m < NHM; ++m) {
        ushort2 uv = *(const ushort2*)(hp + (size_t)m * NHW);
        float vx = bf2f(uv.x), vy = bf2f(uv.y);
        float wv[8];
        *(float4*)&wv[0] = *(const float4*)&wl[m][0];
        *(float4*)&wv[4] = *(const float4*)&wl[m][4];
        #pragma unroll
        for (int j = 0; j < 8; ++j) {
            a0[j] = fmaf(vx, wv[j], a0[j]);
            a1[j] = fmaf(vy, wv[j], a1[j]);
        }
    }
    // out flat index: (b*4096+pix)*64 + wo; fsum NCHW flat aliases same offsets
    size_t ob0 = ((size_t)b * NHW + pix) * 64 + wo0;
    #pragma unroll
    for (int t = 0; t < 2; ++t) {
        float4 r0 = *(const float4*)&fs[ob0 + 4 * t];
        float4 r1 = *(const float4*)&fs[ob0 + 64 + 4 * t];
        float4 w0, w1;
        w0.x = a0[4 * t + 0] + r0.x; w0.y = a0[4 * t + 1] + r0.y;
        w0.z = a0[4 * t + 2] + r0.z; w0.w = a0[4 * t + 3] + r0.w;
        w1.x = a1[4 * t + 0] + r1.x; w1.y = a1[4 * t + 1] + r1.y;
        w1.z = a1[4 * t + 2] + r1.z; w1.w = a1[4 * t + 3] + r1.w;
        *(float4*)&out[ob0 + 4 * t] = w0;
        *(float4*)&out[ob0 + 64 + 4 * t] = w1;
    }
}

extern "C" void kernel_launch(void* const* d_in, const int* in_sizes, int n_in,
                              void* d_out, int out_size, void* d_ws, size_t ws_size,
                              hipStream_t stream) {
    const float* x        = (const float*)d_in[0];
    const float* ln_w     = (const float*)d_in[1];
    const float* ln_b     = (const float*)d_in[2];
    const float* q_w      = (const float*)d_in[3];
    const float* q_b      = (const float*)d_in[4];
    const float* k_w      = (const float*)d_in[5];
    const float* k_b      = (const float*)d_in[6];
    const float* v_w      = (const float*)d_in[7];
    const float* v_b      = (const float*)d_in[8];
    const float* qkdw_w   = (const float*)d_in[9];
    const float* qkdw_b   = (const float*)d_in[10];
    const float* vdw_w    = (const float*)d_in[11];
    const float* vdw_b    = (const float*)d_in[12];
    const float* proj_w   = (const float*)d_in[13];
    const float* proj_b   = (const float*)d_in[14];
    const float* gamma    = (const float*)d_in[15];
    const float* cab_w1   = (const float*)d_in[16];
    const float* cab_b1   = (const float*)d_in[17];
    const float* cab_w2   = (const float*)d_in[18];
    const float* cab_b2   = (const float*)d_in[19];
    const float* ca_w1    = (const float*)d_in[20];
    const float* ca_b1    = (const float*)d_in[21];
    const float* ca_w2    = (const float*)d_in[22];
    const float* ca_b2    = (const float*)d_in[23];
    const float* fc1_w    = (const float*)d_in[24];
    const float* fc1_b    = (const float*)d_in[25];
    const float* fc2_w    = (const float*)d_in[26];
    const float* fc2_b    = (const float*)d_in[27];
    float* out = (float*)d_out;

    char* ws = (char*)d_ws;
    size_t off = 0;
    auto alloc = [&](size_t bytes) { void* p = ws + off; off += (bytes + 255) & ~(size_t)255; return p; };
    unsigned short* xn = (unsigned short*)alloc((size_t)NB * NC * NHW * 2);
    unsigned short* q1 = (unsigned short*)alloc((size_t)NB * NC8 * NHW * 2);
    unsigned short* k1 = (unsigned short*)alloc((size_t)NB * NC8 * NHW * 2);
    unsigned short* v1 = (unsigned short*)alloc((size_t)NB * NC * NHW * 2);
    unsigned short* qdb = (unsigned short*)alloc((size_t)NB * NHW * NC8 * 2);
    unsigned short* kdb = (unsigned short*)alloc((size_t)NB * NHW * NC8 * 2);
    unsigned short* vdb = (unsigned short*)alloc((size_t)NB * NC * NHW * 2);
    unsigned short* O   = (unsigned short*)alloc((size_t)NB * NC * NHW * 2);
    float* y1    = (float*)alloc((size_t)NB * NCC * NHW * 4);
    float* yc    = (float*)alloc((size_t)NB * NC * NHW * 4);
    float* pool  = (float*)alloc(256 * 4);
    float* fsum  = (float*)alloc((size_t)NB * NC * NHW * 4);
    unsigned short* fs1 = (unsigned short*)alloc((size_t)NB * NC * NHW * 2);
    unsigned short* hbuf = (unsigned short*)alloc((size_t)NB * NHM * NHW * 2);
    float* pcab1 = (float*)alloc((size_t)8 * NB * NCC * NHW * 4);
    float* pcab2 = (float*)alloc((size_t)7 * NB * NC * NHW * 4);
    float* wpack = (float*)alloc(49792 * 4);

    float* qkv_wt  = wpack;
    float* cab1_wt = wpack + 5120;
    float* cab2_wt = wpack + 17216;
    float* proj_wt = wpack + 29312;
    float* fc1_wt  = wpack + 33408;
    float* fc2_wt  = wpack + 41600;

    dim3 blk(256);

    k_wt<<<dim3(195), blk, 0, stream>>>(q_w, k_w, v_w, cab_w1, cab_w2, proj_w, fc1_w, fc2_w, wpack, pool);
    k_ln<<<dim3(256), blk, 0, stream>>>(x, ln_w, ln_b, xn);
    k_qkv<<<dim3(8, 8, NB), blk, 0, stream>>>(xn, qkv_wt, q_b, k_b, v_b, q1, k1, v1);
    k_dw3x3_qk<<<dim3(16, 16, NB), blk, 0, stream>>>(q1, k1, qkdw_w, qkdw_b, qdb, kdb);
    k_dw3x3_v<<<dim3(16, NC, NB), blk, 0, stream>>>(v1, vdw_w, vdw_b, vdb);
    k_flash<<<dim3(128, NB), dim3(512), 0, stream>>>(qdb, kdb, vdb, O);
    k_cab1_p<<<dim3(8, 8, NB), blk, 0, stream>>>(xn, cab1_wt, pcab1);
    k_cab1_c<<<dim3(16, NCC, NB), blk, 0, stream>>>(pcab1, cab_b1, y1);
    k_cab2_p<<<dim3(8, 14, NB), blk, 0, stream>>>(y1, cab2_wt, pcab2);
    k_cab2_c<<<dim3(16, NC, NB), blk, 0, stream>>>(pcab2, cab_b2, yc, pool);
    k_fsum2<<<dim3(8, 8, NB), blk, 0, stream>>>(O, proj_wt, proj_b, gamma, xn, yc, pool,
                                                ca_w1, ca_b1, ca_w2, ca_b2, x, fsum);
    k_ln<<<dim3(256), blk, 0, stream>>>(fsum, ln_w, ln_b, fs1);
    k_mlp1<<<dim3(8, 16, NB), blk, 0, stream>>>(fs1, fc1_wt, fc1_b, hbuf);
    k_mlp2<<<dim3(8, 8, NB), blk, 0, stream>>>(hbuf, fc2_wt, fc2_b, fsum, out);
}

// Round 14
// 244.486 us; speedup vs baseline: 1.0696x; 1.0696x over previous
//
#include <hip/hip_runtime.h>
#include <math.h>

#define NB 4
#define NC 64
#define NC8 8
#define NCC 21
#define NHW 4096
#define NHM 128

typedef __attribute__((ext_vector_type(8))) short bf16x8;
typedef __attribute__((ext_vector_type(4))) float f32x4;

__device__ __forceinline__ float gelu_exact(float x) {
    return 0.5f * x * (1.0f + erff(x * 0.70710678118654752f));
}

__device__ __forceinline__ unsigned short f2bf(float x) {
    union { float f; unsigned u; } u; u.f = x;
    unsigned r = u.u + 0x7fffu + ((u.u >> 16) & 1u);   // RNE
    return (unsigned short)(r >> 16);
}

__device__ __forceinline__ float bf2f(unsigned short v) {
    union { unsigned u; float f; } t; t.u = (unsigned)v << 16; return t.f;
}

// ---------------- weight pack/transpose into [ci][co] layouts; zero pool ----------------
// o: [0) qkv 5120 | [5120) cab1 12096 | [17216) cab2 12096 | [29312) proj 4096
//    [33408) fc1 8192 | [41600) fc2 8192
__global__ void k_wt(const float* __restrict__ qw, const float* __restrict__ kw,
                     const float* __restrict__ vw, const float* __restrict__ c1w,
                     const float* __restrict__ c2w, const float* __restrict__ pw,
                     const float* __restrict__ f1w, const float* __restrict__ f2w,
                     float* __restrict__ o, float* __restrict__ pool) {
    int idx = blockIdx.x * 256 + threadIdx.x;
    if (idx < 256) pool[idx] = 0.f;
    if (idx < 5120) {
        int ci = idx / 80, j = idx - ci * 80;
        float v = j < 8 ? qw[j * 64 + ci] : (j < 16 ? kw[(j - 8) * 64 + ci] : vw[(j - 16) * 64 + ci]);
        o[idx] = v;
    } else if (idx < 17216) {
        int r = idx - 5120; int co = r % 21, q = r / 21; int ci = q / 9, t = q - ci * 9;
        o[idx] = c1w[co * 576 + ci * 9 + t];
    } else if (idx < 29312) {
        int r = idx - 17216; int co = r & 63, q = r >> 6; int ci = q / 9, t = q - ci * 9;
        o[idx] = c2w[co * 189 + ci * 9 + t];
    } else if (idx < 33408) {
        int r = idx - 29312; int co = r & 63, ci = r >> 6;
        o[idx] = pw[co * 64 + ci];
    } else if (idx < 41600) {
        int r = idx - 33408; int m = r & 127, c = r >> 7;
        o[idx] = f1w[m * 64 + c];
    } else if (idx < 49792) {
        int r = idx - 41600; int wo = r & 63, m = r >> 6;
        o[idx] = f2w[wo * 128 + m];
    }
}

// ---------------- LayerNorm over channel dim; 4 threads per pixel; bf16 out ----------------
__global__ __launch_bounds__(256) void k_ln(const float* __restrict__ in, const float* __restrict__ w,
                                            const float* __restrict__ bb, unsigned short* __restrict__ out) {
    __shared__ float r1[4][64], r2[4][64];
    int tid = threadIdx.x;
    int pl = tid & 63, cq = tid >> 6;
    int b = blockIdx.x >> 6;
    int pix = (blockIdx.x & 63) * 64 + pl;
    const float* p = in + (size_t)b * NC * NHW + pix;
    float v[16]; float s = 0.f, ss = 0.f;
    #pragma unroll
    for (int k = 0; k < 16; ++k) {
        float f = p[(size_t)(cq * 16 + k) * NHW];
        v[k] = f; s += f; ss += f * f;
    }
    r1[cq][pl] = s; r2[cq][pl] = ss;
    __syncthreads();
    float S  = r1[0][pl] + r1[1][pl] + r1[2][pl] + r1[3][pl];
    float SS = r2[0][pl] + r2[1][pl] + r2[2][pl] + r2[3][pl];
    float mean = S * (1.0f / 64);
    float rstd = rsqrtf(SS * (1.0f / 64) - mean * mean + 1e-5f);
    unsigned short* q = out + (size_t)b * NC * NHW + pix;
    #pragma unroll
    for (int k = 0; k < 16; ++k) {
        int c = cq * 16 + k;
        q[(size_t)c * NHW] = f2bf((v[k] - mean) * rstd * w[c] + bb[c]);
    }
}

// ---------------- q/k/v 1x1 convs: LDS-tiled full-output GEMM (input read ONCE) ----------------
// Block = 512 thr, 64-pixel tile, all 80 outputs. Xs 8KB + Ws 20KB LDS.
__global__ __launch_bounds__(512) void k_qkv(const unsigned short* __restrict__ xn,
        const float* __restrict__ wt, const float* __restrict__ qb,
        const float* __restrict__ kb, const float* __restrict__ vb,
        unsigned short* __restrict__ q1, unsigned short* __restrict__ k1,
        unsigned short* __restrict__ v1) {
    __shared__ unsigned short Xs[64][64];
    __shared__ float Ws[64][80];
    int tid = threadIdx.x;
    int pix0 = blockIdx.x * 64, b = blockIdx.y;
    for (int i = tid; i < 1024; i += 512) {
        int c = i >> 4, q4 = i & 15;
        *(ushort4*)&Xs[c][q4 * 4] = *(const ushort4*)(xn + ((size_t)b * NC + c) * NHW + pix0 + q4 * 4);
    }
    for (int i = tid; i < 1280; i += 512)
        *(float4*)&((float*)Ws)[i * 4] = *(const float4*)&wt[i * 4];
    __syncthreads();
    int p2 = (tid & 31) * 2, g = tid >> 5;   // 16 groups x 5 co
    int co0 = g * 5;
    float a0[5], a1[5];
    #pragma unroll
    for (int j = 0; j < 5; ++j) { a0[j] = 0.f; a1[j] = 0.f; }
    for (int ci = 0; ci < 64; ++ci) {
        ushort2 uv = *(const ushort2*)&Xs[ci][p2];
        float fx = bf2f(uv.x), fy = bf2f(uv.y);
        #pragma unroll
        for (int j = 0; j < 5; ++j) {
            float wv = Ws[ci][co0 + j];
            a0[j] = fmaf(fx, wv, a0[j]);
            a1[j] = fmaf(fy, wv, a1[j]);
        }
    }
    #pragma unroll
    for (int j = 0; j < 5; ++j) {
        int co = co0 + j;
        float bsv; unsigned short* dst;
        if (co < 8)       { bsv = qb[co];      dst = q1 + ((size_t)b * NC8 + co) * NHW + pix0 + p2; }
        else if (co < 16) { bsv = kb[co - 8];  dst = k1 + ((size_t)b * NC8 + co - 8) * NHW + pix0 + p2; }
        else              { bsv = vb[co - 16]; dst = v1 + ((size_t)b * NC + co - 16) * NHW + pix0 + p2; }
        ushort2 o = { f2bf(a0[j] + bsv), f2bf(a1[j] + bsv) };
        *(ushort2*)dst = o;
    }
}

// ---------------- depthwise 3x3, q+k merged: bf16 in, bf16 out, (b,pix,8) layout ----------------
__global__ void k_dw3x3_qk(const unsigned short* __restrict__ q1, const unsigned short* __restrict__ k1,
                           const float* __restrict__ w, const float* __restrict__ bias,
                           unsigned short* __restrict__ qdb, unsigned short* __restrict__ kdb) {
    int pix = blockIdx.x * blockDim.x + threadIdx.x;
    int cy = blockIdx.y, b = blockIdx.z;
    int c = cy & 7;
    const unsigned short* ip = (cy < 8 ? q1 : k1) + ((size_t)b * NC8 + c) * NHW;
    unsigned short* outT = (cy < 8 ? qdb : kdb);
    int y = pix >> 6, x = pix & 63;
    const float* wp = w + c * 9;
    float acc = bias[c];
    #pragma unroll
    for (int dy = -1; dy <= 1; ++dy) {
        int yy = y + dy; if (yy < 0 || yy > 63) continue;
        #pragma unroll
        for (int dx = -1; dx <= 1; ++dx) {
            int xx = x + dx; if (xx < 0 || xx > 63) continue;
            acc += wp[(dy + 1) * 3 + (dx + 1)] * bf2f(ip[yy * 64 + xx]);
        }
    }
    outT[((size_t)b * NHW + pix) * NC8 + c] = f2bf(acc);
}

// ---------------- depthwise 3x3, v path: bf16 in/out, chunked layout V8[b][pix>>3][c][pix&7] ----------------
__global__ void k_dw3x3_v(const unsigned short* __restrict__ in, const float* __restrict__ w,
                          const float* __restrict__ bias, unsigned short* __restrict__ v8) {
    int pix = blockIdx.x * blockDim.x + threadIdx.x;
    int c = blockIdx.y, b = blockIdx.z;
    int y = pix >> 6, x = pix & 63;
    const unsigned short* ip = in + ((size_t)b * NC + c) * NHW;
    const float* wp = w + c * 9;
    float acc = bias[c];
    #pragma unroll
    for (int dy = -1; dy <= 1; ++dy) {
        int yy = y + dy; if (yy < 0 || yy > 63) continue;
        #pragma unroll
        for (int dx = -1; dx <= 1; ++dx) {
            int xx = x + dx; if (xx < 0 || xx > 63) continue;
            acc += wp[(dy + 1) * 3 + (dx + 1)] * bf2f(ip[yy * 64 + xx]);
        }
    }
    v8[(((size_t)b * 512 + (pix >> 3)) * NC + c) * 8 + (pix & 7)] = f2bf(acc);
}

// ---------------- flash attention: 8 waves/block, i-tile x2 in-wave, chunked-V, LDS union ----------------
__global__ __launch_bounds__(512) void k_flash(const unsigned short* __restrict__ qdb,
                                               const unsigned short* __restrict__ kdb,
                                               const unsigned short* __restrict__ v8,
                                               unsigned short* __restrict__ O) {
    __shared__ __align__(16) char smem[35840];  // max(Pl 8*2304=18432, Ocmb 16*1088*2=34816 + Lw 1024)
    int tid = threadIdx.x;
    int w = tid >> 6, lane = tid & 63;
    int g = lane >> 4, il = lane & 15;
    int i0 = blockIdx.x * 32, b = blockIdx.y;

    unsigned short (*P)[72] = (unsigned short (*)[72])(smem + w * 2304);

    bf16x8 qb0 = (bf16x8)(short)0, qb1 = (bf16x8)(short)0;
    if (g == 0) {
        qb0 = *(const bf16x8*)(qdb + (size_t)(b * NHW + i0 + il) * NC8);
        qb1 = *(const bf16x8*)(qdb + (size_t)(b * NHW + i0 + 16 + il) * NC8);
    }

    f32x4 acc0[4], acc1[4];
    #pragma unroll
    for (int ct = 0; ct < 4; ++ct) {
        acc0[ct] = (f32x4){0.f, 0.f, 0.f, 0.f};
        acc1[ct] = (f32x4){0.f, 0.f, 0.f, 0.f};
    }
    float La0 = 0.f, La1 = 0.f;

    bf16x8 kn[4];
    #pragma unroll
    for (int t = 0; t < 4; ++t) {
        kn[t] = (bf16x8)(short)0;
        if (g == 0) kn[t] = *(const bf16x8*)(kdb + (size_t)(b * NHW + w * 512 + 16 * t + il) * NC8);
    }

    for (int jt = 0; jt < 8; ++jt) {
        int j0 = w * 512 + jt * 64;
        int ch0 = b * 512 + (j0 >> 3);
        bf16x8 va[2][4];
        #pragma unroll
        for (int kc = 0; kc < 2; ++kc)
            #pragma unroll
            for (int ct = 0; ct < 4; ++ct)
                va[kc][ct] = *(const bf16x8*)(v8 +
                    ((size_t)(ch0 + kc * 4 + g) * NC + ct * 16 + il) * 8);
        bf16x8 ka[4];
        #pragma unroll
        for (int t = 0; t < 4; ++t) ka[t] = kn[t];
        if (jt < 7) {
            #pragma unroll
            for (int t = 0; t < 4; ++t) {
                kn[t] = (bf16x8)(short)0;
                if (g == 0) kn[t] = *(const bf16x8*)(kdb + (size_t)(b * NHW + j0 + 64 + 16 * t + il) * NC8);
            }
        }
        // ---- strip 0 ----
        #pragma unroll
        for (int t = 0; t < 4; ++t) {
            f32x4 sv = __builtin_amdgcn_mfma_f32_16x16x32_bf16(ka[t], qb0, (f32x4){0.f, 0.f, 0.f, 0.f}, 0, 0, 0);
            float p0 = __expf(sv[0]), p1 = __expf(sv[1]);
            float p2 = __expf(sv[2]), p3 = __expf(sv[3]);
            La0 += (p0 + p1) + (p2 + p3);
            ushort4 pk;
            pk.x = f2bf(p0); pk.y = f2bf(p1); pk.z = f2bf(p2); pk.w = f2bf(p3);
            *(ushort4*)&P[il][16 * t + 4 * g] = pk;
        }
        #pragma unroll
        for (int kc = 0; kc < 2; ++kc) {
            bf16x8 pb = *(const bf16x8*)&P[il][kc * 32 + 8 * g];
            #pragma unroll
            for (int ct = 0; ct < 4; ++ct)
                acc0[ct] = __builtin_amdgcn_mfma_f32_16x16x32_bf16(va[kc][ct], pb, acc0[ct], 0, 0, 0);
        }
        // ---- strip 1 (reuse P, same ka/va) ----
        #pragma unroll
        for (int t = 0; t < 4; ++t) {
            f32x4 sv = __builtin_amdgcn_mfma_f32_16x16x32_bf16(ka[t], qb1, (f32x4){0.f, 0.f, 0.f, 0.f}, 0, 0, 0);
            float p0 = __expf(sv[0]), p1 = __expf(sv[1]);
            float p2 = __expf(sv[2]), p3 = __expf(sv[3]);
            La1 += (p0 + p1) + (p2 + p3);
            ushort4 pk;
            pk.x = f2bf(p0); pk.y = f2bf(p1); pk.z = f2bf(p2); pk.w = f2bf(p3);
            *(ushort4*)&P[il][16 * t + 4 * g] = pk;
        }
        #pragma unroll
        for (int kc = 0; kc < 2; ++kc) {
            bf16x8 pb = *(const bf16x8*)&P[il][kc * 32 + 8 * g];
            #pragma unroll
            for (int ct = 0; ct < 4; ++ct)
                acc1[ct] = __builtin_amdgcn_mfma_f32_16x16x32_bf16(va[kc][ct], pb, acc1[ct], 0, 0, 0);
        }
    }
    La0 += __shfl_xor(La0, 16, 64); La0 += __shfl_xor(La0, 32, 64);
    La1 += __shfl_xor(La1, 16, 64); La1 += __shfl_xor(La1, 32, 64);

    __syncthreads();   // all waves done with P before Ocmb overlays it
    unsigned short* Ocm = (unsigned short*)smem;           // [16][64*17] bf16 (waveslot = w*2+strip)
    float* Lw = (float*)(smem + 34816);                    // [16][16]
    #pragma unroll
    for (int ct = 0; ct < 4; ++ct)
        #pragma unroll
        for (int e = 0; e < 4; ++e) {
            int c = ct * 16 + 4 * g + e;
            Ocm[(w * 2 + 0) * 1088 + c * 17 + il] = f2bf(acc0[ct][e]);
            Ocm[(w * 2 + 1) * 1088 + c * 17 + il] = f2bf(acc1[ct][e]);
        }
    if (lane < 16) {
        Lw[(w * 2 + 0) * 16 + il] = La0;
        Lw[(w * 2 + 1) * 16 + il] = La1;
    }
    __syncthreads();

    int st = tid >> 8, rem = tid & 255;    // strip, then 16 i x 16 ch
    int ic = rem & 15, ch = rem >> 4;
    float l = 0.f;
    #pragma unroll
    for (int w2 = 0; w2 < 8; ++w2) l += Lw[(w2 * 2 + st) * 16 + ic];
    float rl = 1.0f / l;
    #pragma unroll
    for (int cc = 0; cc < 4; ++cc) {
        int c = cc * 16 + ch;
        float o = 0.f;
        #pragma unroll
        for (int w2 = 0; w2 < 8; ++w2) o += bf2f(Ocm[(w2 * 2 + st) * 1088 + c * 17 + ic]);
        O[(size_t)(b * NC + c) * NHW + i0 + st * 16 + ic] = f2bf(o * rl);
    }
}

// ---------------- CAB conv1 3x3 (64->21), bf16 in, K-split x8, LDS weights, 2 pix ----------------
__global__ __launch_bounds__(256) void k_cab1_p(const unsigned short* __restrict__ xn,
        const float* __restrict__ wt, float* __restrict__ part) {
    __shared__ float wl[72][24];
    int tid = threadIdx.x;
    int s = blockIdx.y, b = blockIdx.z;
    for (int idx = tid; idx < 432; idx += 256) {
        int lt = idx / 6, j4 = idx % 6;
        int ci = s * 8 + lt / 9, t = lt % 9;
        float4 v;
        v.x = (j4 * 4 + 0 < 21) ? wt[(ci * 9 + t) * 21 + j4 * 4 + 0] : 0.f;
        v.y = (j4 * 4 + 1 < 21) ? wt[(ci * 9 + t) * 21 + j4 * 4 + 1] : 0.f;
        v.z = (j4 * 4 + 2 < 21) ? wt[(ci * 9 + t) * 21 + j4 * 4 + 2] : 0.f;
        v.w = (j4 * 4 + 3 < 21) ? wt[(ci * 9 + t) * 21 + j4 * 4 + 3] : 0.f;
        *(float4*)&wl[lt][j4 * 4] = v;
    }
    __syncthreads();
    int pix = (blockIdx.x * 256 + tid) * 2;
    int y = pix >> 6, x0 = pix & 63;
    float a0[21], a1[21];
    #pragma unroll
    for (int co = 0; co < 21; ++co) { a0[co] = 0.f; a1[co] = 0.f; }
    const unsigned short* ip0 = xn + (size_t)b * NC * NHW;
    for (int cc = 0; cc < 8; ++cc) {
        const unsigned short* ip = ip0 + (size_t)(s * 8 + cc) * NHW;
        #pragma unroll
        for (int dy = -1; dy <= 1; ++dy) {
            int yy = y + dy;
            bool yok = (unsigned)yy < 64u;
            #pragma unroll
            for (int dx = -1; dx <= 1; ++dx) {
                int xx0 = x0 + dx, xx1 = x0 + 1 + dx;
                float v0 = (yok && (unsigned)xx0 < 64u) ? bf2f(ip[yy * 64 + xx0]) : 0.f;
                float v1 = (yok && (unsigned)xx1 < 64u) ? bf2f(ip[yy * 64 + xx1]) : 0.f;
                const float* wr = wl[cc * 9 + (dy + 1) * 3 + (dx + 1)];
                float wv[24];
                *(float4*)&wv[0]  = *(const float4*)&wr[0];
                *(float4*)&wv[4]  = *(const float4*)&wr[4];
                *(float4*)&wv[8]  = *(const float4*)&wr[8];
                *(float4*)&wv[12] = *(const float4*)&wr[12];
                *(float4*)&wv[16] = *(const float4*)&wr[16];
                *(float4*)&wv[20] = *(const float4*)&wr[20];
                #pragma unroll
                for (int co = 0; co < 21; ++co) {
                    a0[co] = fmaf(v0, wv[co], a0[co]);
                    a1[co] = fmaf(v1, wv[co], a1[co]);
                }
            }
        }
    }
    size_t ob = ((size_t)(s * NB + b) * NCC) * NHW + pix;
    #pragma unroll
    for (int co = 0; co < 21; ++co) {
        float2 o = { a0[co], a1[co] };
        *(float2*)&part[ob + (size_t)co * NHW] = o;
    }
}

__global__ void k_cab1_c(const float* __restrict__ part, const float* __restrict__ bias,
                         float* __restrict__ y1) {
    int pix = blockIdx.x * 256 + threadIdx.x;
    int co = blockIdx.y, b = blockIdx.z;
    float s = bias[co];
    #pragma unroll
    for (int sp = 0; sp < 8; ++sp)
        s += part[((size_t)(sp * NB + b) * NCC + co) * NHW + pix];
    y1[((size_t)b * NCC + co) * NHW + pix] = gelu_exact(s);
}

// ---------------- CAB conv2 3x3 (21->64), K-split x7 * co-split x2, LDS weights, 2 pix ----------------
__global__ __launch_bounds__(256) void k_cab2_p(const float* __restrict__ y1,
        const float* __restrict__ wt, float* __restrict__ part) {
    __shared__ float wl[27][32];
    int tid = threadIdx.x;
    int s = blockIdx.y >> 1, co0 = (blockIdx.y & 1) * 32, b = blockIdx.z;
    for (int idx = tid; idx < 216; idx += 256) {
        int lt = idx >> 3, j4 = idx & 7;
        int ci = s * 3 + lt / 9, t = lt % 9;
        *(float4*)&wl[lt][j4 * 4] = *(const float4*)&wt[(ci * 9 + t) * 64 + co0 + j4 * 4];
    }
    __syncthreads();
    int pix = (blockIdx.x * 256 + tid) * 2;
    int y = pix >> 6, x0 = pix & 63;
    float a0[32], a1[32];
    #pragma unroll
    for (int co = 0; co < 32; ++co) { a0[co] = 0.f; a1[co] = 0.f; }
    const float* ip0 = y1 + (size_t)b * NCC * NHW;
    for (int cc = 0; cc < 3; ++cc) {
        const float* ip = ip0 + (size_t)(s * 3 + cc) * NHW;
        #pragma unroll
        for (int dy = -1; dy <= 1; ++dy) {
            int yy = y + dy;
            bool yok = (unsigned)yy < 64u;
            #pragma unroll
            for (int dx = -1; dx <= 1; ++dx) {
                int xx0 = x0 + dx, xx1 = x0 + 1 + dx;
                float v0 = (yok && (unsigned)xx0 < 64u) ? ip[yy * 64 + xx0] : 0.f;
                float v1 = (yok && (unsigned)xx1 < 64u) ? ip[yy * 64 + xx1] : 0.f;
                const float* wr = wl[cc * 9 + (dy + 1) * 3 + (dx + 1)];
                float wv[32];
                #pragma unroll
                for (int h = 0; h < 8; ++h)
                    *(float4*)&wv[h * 4] = *(const float4*)&wr[h * 4];
                #pragma unroll
                for (int co = 0; co < 32; ++co) {
                    a0[co] = fmaf(v0, wv[co], a0[co]);
                    a1[co] = fmaf(v1, wv[co], a1[co]);
                }
            }
        }
    }
    size_t ob = ((size_t)(s * NB + b) * NC + co0) * NHW + pix;
    #pragma unroll
    for (int co = 0; co < 32; ++co) {
        float2 o = { a0[co], a1[co] };
        *(float2*)&part[ob + (size_t)co * NHW] = o;
    }
}

// ---------------- combine cab2 partials + fused global-avg-pool (atomic into zeroed pool) ----------------
__global__ void k_cab2_c(const float* __restrict__ part, const float* __restrict__ bias,
                         float* __restrict__ yc, float* __restrict__ pool) {
    __shared__ float red[256];
    int tid = threadIdx.x;
    int pix = blockIdx.x * 256 + tid;
    int co = blockIdx.y, b = blockIdx.z;
    float s = bias[co];
    #pragma unroll
    for (int sp = 0; sp < 7; ++sp)
        s += part[((size_t)(sp * NB + b) * NC + co) * NHW + pix];
    yc[((size_t)b * NC + co) * NHW + pix] = s;
    red[tid] = s;
    __syncthreads();
    for (int st = 128; st > 0; st >>= 1) {
        if (tid < st) red[tid] += red[tid + st];
        __syncthreads();
    }
    if (tid == 0) atomicAdd(&pool[b * NC + co], red[0]);
}

// ---------------- proj + CA + residuals: LDS-tiled full-output (O read ONCE) ----------------
// Block = 512 thr, 64-pixel tile, all 64 co. Os 8KB + Ws 16KB.
__global__ __launch_bounds__(512) void k_fsum2(const unsigned short* __restrict__ O,
        const float* __restrict__ pwt, const float* __restrict__ pb,
        const float* __restrict__ gamma, const unsigned short* __restrict__ xn,
        const float* __restrict__ yc, const float* __restrict__ pool,
        const float* __restrict__ cw1, const float* __restrict__ cb1,
        const float* __restrict__ cw2, const float* __restrict__ cb2,
        const float* __restrict__ x, float* __restrict__ fsum) {
    __shared__ unsigned short Os[64][64];
    __shared__ float Ws[64][64];
    int tid = threadIdx.x;
    int pix0 = blockIdx.x * 64, b = blockIdx.y;
    for (int i = tid; i < 1024; i += 512) {
        int c = i >> 4, q4 = i & 15;
        *(ushort4*)&Os[c][q4 * 4] = *(const ushort4*)(O + ((size_t)b * NC + c) * NHW + pix0 + q4 * 4);
    }
    for (int i = tid; i < 1024; i += 512)
        *(float4*)&((float*)Ws)[i * 4] = *(const float4*)&pwt[i * 4];
    __syncthreads();
    // channel attention (uniform per block)
    float h0 = cb1[0], h1 = cb1[1];
    for (int ci = 0; ci < NC; ++ci) {
        float pv = pool[b * NC + ci] * (1.0f / NHW);
        h0 += cw1[ci] * pv;
        h1 += cw1[NC + ci] * pv;
    }
    h0 = fmaxf(h0, 0.f); h1 = fmaxf(h1, 0.f);
    int p2 = (tid & 31) * 2, g = tid >> 5;   // 16 groups x 4 co
    int co0 = g * 4;
    float scv[4];
    #pragma unroll
    for (int j = 0; j < 4; ++j) {
        int c = co0 + j;
        float z = cw2[c * 2] * h0 + cw2[c * 2 + 1] * h1 + cb2[c];
        scv[j] = 1.0f / (1.0f + __expf(-z));
    }
    float a0[4], a1[4];
    #pragma unroll
    for (int j = 0; j < 4; ++j) { a0[j] = 0.f; a1[j] = 0.f; }
    for (int ci = 0; ci < 64; ++ci) {
        ushort2 uv = *(const ushort2*)&Os[ci][p2];
        float ox = bf2f(uv.x), oy = bf2f(uv.y);
        float wv[4];
        *(float4*)wv = *(const float4*)&Ws[ci][co0];
        #pragma unroll
        for (int j = 0; j < 4; ++j) {
            a0[j] = fmaf(ox, wv[j], a0[j]);
            a1[j] = fmaf(oy, wv[j], a1[j]);
        }
    }
    float gg = gamma[0];
    size_t base = (size_t)b * NC * NHW + pix0 + p2;
    #pragma unroll
    for (int j = 0; j < 4; ++j) {
        int c = co0 + j;
        size_t n = base + (size_t)c * NHW;
        float pbv = pb[c];
        ushort2 xnu = *(const ushort2*)&xn[n];
        float2 ycv = *(const float2*)&yc[n];
        float2 xv  = *(const float2*)&x[n];
        float2 o = { gg * (a0[j] + pbv) + bf2f(xnu.x) + ycv.x * scv[j] + xv.x,
                     gg * (a1[j] + pbv) + bf2f(xnu.y) + ycv.y * scv[j] + xv.y };
        *(float2*)&fsum[n] = o;
    }
}

// ---------------- MLP fc1 + gelu: LDS-tiled full-output (fs1 read ONCE) ----------------
// Block = 512 thr, 64-pixel tile, all 128 m. Fs 8KB + Ws 32KB.
__global__ __launch_bounds__(512) void k_mlp1(const unsigned short* __restrict__ fs1,
        const float* __restrict__ wt, const float* __restrict__ bias,
        unsigned short* __restrict__ h) {
    __shared__ unsigned short Fs[64][64];
    __shared__ float Ws[64][128];
    int tid = threadIdx.x;
    int pix0 = blockIdx.x * 64, b = blockIdx.y;
    for (int i = tid; i < 1024; i += 512) {
        int c = i >> 4, q4 = i & 15;
        *(ushort4*)&Fs[c][q4 * 4] = *(const ushort4*)(fs1 + ((size_t)b * NC + c) * NHW + pix0 + q4 * 4);
    }
    for (int i = tid; i < 2048; i += 512)
        *(float4*)&((float*)Ws)[i * 4] = *(const float4*)&wt[i * 4];
    __syncthreads();
    int p2 = (tid & 31) * 2, g = tid >> 5;   // 16 groups x 8 m
    int m0 = g * 8;
    float a0[8], a1[8];
    #pragma unroll
    for (int j = 0; j < 8; ++j) { float bv = bias[m0 + j]; a0[j] = bv; a1[j] = bv; }
    for (int c = 0; c < 64; ++c) {
        ushort2 uv = *(const ushort2*)&Fs[c][p2];
        float vx = bf2f(uv.x), vy = bf2f(uv.y);
        float wv[8];
        *(float4*)&wv[0] = *(const float4*)&Ws[c][m0];
        *(float4*)&wv[4] = *(const float4*)&Ws[c][m0 + 4];
        #pragma unroll
        for (int j = 0; j < 8; ++j) {
            a0[j] = fmaf(vx, wv[j], a0[j]);
            a1[j] = fmaf(vy, wv[j], a1[j]);
        }
    }
    unsigned short* hp = h + (size_t)b * NHM * NHW + pix0 + p2;
    #pragma unroll
    for (int j = 0; j < 8; ++j) {
        ushort2 o = { f2bf(gelu_exact(a0[j])), f2bf(gelu_exact(a1[j])) };
        *(ushort2*)(hp + (size_t)(m0 + j) * NHW) = o;
    }
}

// ---------------- MLP fc2 + raw-view permutation + residual: LDS-tiled (hbuf read ONCE) ----------------
// Block = 512 thr, 64-pixel tile, all 64 wo. Hs 16KB + Ws 32KB.
__global__ __launch_bounds__(512) void k_mlp2(const unsigned short* __restrict__ h,
        const float* __restrict__ wt, const float* __restrict__ bias,
        const float* __restrict__ fs, float* __restrict__ out) {
    __shared__ unsigned short Hs[128][64];
    __shared__ float Ws[128][64];
    int tid = threadIdx.x;
    int pix0 = blockIdx.x * 64, b = blockIdx.y;
    for (int i = tid; i < 2048; i += 512) {
        int m = i >> 4, q4 = i & 15;
        *(ushort4*)&Hs[m][q4 * 4] = *(const ushort4*)(h + ((size_t)b * NHM + m) * NHW + pix0 + q4 * 4);
    }
    for (int i = tid; i < 2048; i += 512)
        *(float4*)&((float*)Ws)[i * 4] = *(const float4*)&wt[i * 4];
    __syncthreads();
    int p2 = (tid & 31) * 2, g = tid >> 5;   // 16 groups x 4 wo
    int wo0 = g * 4;
    float a0[4], a1[4];
    #pragma unroll
    for (int j = 0; j < 4; ++j) { float bv = bias[wo0 + j]; a0[j] = bv; a1[j] = bv; }
    for (int m = 0; m < 128; ++m) {
        ushort2 uv = *(const ushort2*)&Hs[m][p2];
        float vx = bf2f(uv.x), vy = bf2f(uv.y);
        float wv[4];
        *(float4*)wv = *(const float4*)&Ws[m][wo0];
        #pragma unroll
        for (int j = 0; j < 4; ++j) {
            a0[j] = fmaf(vx, wv[j], a0[j]);
            a1[j] = fmaf(vy, wv[j], a1[j]);
        }
    }
    // out flat index: (b*4096+pix)*64 + wo; fsum NCHW flat aliases same offsets
    size_t ob0 = ((size_t)b * NHW + pix0 + p2) * 64 + wo0;
    float4 r0 = *(const float4*)&fs[ob0];
    float4 r1 = *(const float4*)&fs[ob0 + 64];
    float4 w0, w1;
    w0.x = a0[0] + r0.x; w0.y = a0[1] + r0.y; w0.z = a0[2] + r0.z; w0.w = a0[3] + r0.w;
    w1.x = a1[0] + r1.x; w1.y = a1[1] + r1.y; w1.z = a1[2] + r1.z; w1.w = a1[3] + r1.w;
    *(float4*)&out[ob0] = w0;
    *(float4*)&out[ob0 + 64] = w1;
}

extern "C" void kernel_launch(void* const* d_in, const int* in_sizes, int n_in,
                              void* d_out, int out_size, void* d_ws, size_t ws_size,
                              hipStream_t stream) {
    const float* x        = (const float*)d_in[0];
    const float* ln_w     = (const float*)d_in[1];
    const float* ln_b     = (const float*)d_in[2];
    const float* q_w      = (const float*)d_in[3];
    const float* q_b      = (const float*)d_in[4];
    const float* k_w      = (const float*)d_in[5];
    const float* k_b      = (const float*)d_in[6];
    const float* v_w      = (const float*)d_in[7];
    const float* v_b      = (const float*)d_in[8];
    const float* qkdw_w   = (const float*)d_in[9];
    const float* qkdw_b   = (const float*)d_in[10];
    const float* vdw_w    = (const float*)d_in[11];
    const float* vdw_b    = (const float*)d_in[12];
    const float* proj_w   = (const float*)d_in[13];
    const float* proj_b   = (const float*)d_in[14];
    const float* gamma    = (const float*)d_in[15];
    const float* cab_w1   = (const float*)d_in[16];
    const float* cab_b1   = (const float*)d_in[17];
    const float* cab_w2   = (const float*)d_in[18];
    const float* cab_b2   = (const float*)d_in[19];
    const float* ca_w1    = (const float*)d_in[20];
    const float* ca_b1    = (const float*)d_in[21];
    const float* ca_w2    = (const float*)d_in[22];
    const float* ca_b2    = (const float*)d_in[23];
    const float* fc1_w    = (const float*)d_in[24];
    const float* fc1_b    = (const float*)d_in[25];
    const float* fc2_w    = (const float*)d_in[26];
    const float* fc2_b    = (const float*)d_in[27];
    float* out = (float*)d_out;

    char* ws = (char*)d_ws;
    size_t off = 0;
    auto alloc = [&](size_t bytes) { void* p = ws + off; off += (bytes + 255) & ~(size_t)255; return p; };
    unsigned short* xn = (unsigned short*)alloc((size_t)NB * NC * NHW * 2);
    unsigned short* q1 = (unsigned short*)alloc((size_t)NB * NC8 * NHW * 2);
    unsigned short* k1 = (unsigned short*)alloc((size_t)NB * NC8 * NHW * 2);
    unsigned short* v1 = (unsigned short*)alloc((size_t)NB * NC * NHW * 2);
    unsigned short* qdb = (unsigned short*)alloc((size_t)NB * NHW * NC8 * 2);
    unsigned short* kdb = (unsigned short*)alloc((size_t)NB * NHW * NC8 * 2);
    unsigned short* vdb = (unsigned short*)alloc((size_t)NB * NC * NHW * 2);
    unsigned short* O   = (unsigned short*)alloc((size_t)NB * NC * NHW * 2);
    float* y1    = (float*)alloc((size_t)NB * NCC * NHW * 4);
    float* yc    = (float*)alloc((size_t)NB * NC * NHW * 4);
    float* pool  = (float*)alloc(256 * 4);
    float* fsum  = (float*)alloc((size_t)NB * NC * NHW * 4);
    unsigned short* fs1 = (unsigned short*)alloc((size_t)NB * NC * NHW * 2);
    unsigned short* hbuf = (unsigned short*)alloc((size_t)NB * NHM * NHW * 2);
    float* pcab1 = (float*)alloc((size_t)8 * NB * NCC * NHW * 4);
    float* pcab2 = (float*)alloc((size_t)7 * NB * NC * NHW * 4);
    float* wpack = (float*)alloc(49792 * 4);

    float* qkv_wt  = wpack;
    float* cab1_wt = wpack + 5120;
    float* cab2_wt = wpack + 17216;
    float* proj_wt = wpack + 29312;
    float* fc1_wt  = wpack + 33408;
    float* fc2_wt  = wpack + 41600;

    dim3 blk(256);
    dim3 blk5(512);

    k_wt<<<dim3(195), blk, 0, stream>>>(q_w, k_w, v_w, cab_w1, cab_w2, proj_w, fc1_w, fc2_w, wpack, pool);
    k_ln<<<dim3(256), blk, 0, stream>>>(x, ln_w, ln_b, xn);
    k_qkv<<<dim3(64, NB), blk5, 0, stream>>>(xn, qkv_wt, q_b, k_b, v_b, q1, k1, v1);
    k_dw3x3_qk<<<dim3(16, 16, NB), blk, 0, stream>>>(q1, k1, qkdw_w, qkdw_b, qdb, kdb);
    k_dw3x3_v<<<dim3(16, NC, NB), blk, 0, stream>>>(v1, vdw_w, vdw_b, vdb);
    k_flash<<<dim3(128, NB), blk5, 0, stream>>>(qdb, kdb, vdb, O);
    k_cab1_p<<<dim3(8, 8, NB), blk, 0, stream>>>(xn, cab1_wt, pcab1);
    k_cab1_c<<<dim3(16, NCC, NB), blk, 0, stream>>>(pcab1, cab_b1, y1);
    k_cab2_p<<<dim3(8, 14, NB), blk, 0, stream>>>(y1, cab2_wt, pcab2);
    k_cab2_c<<<dim3(16, NC, NB), blk, 0, stream>>>(pcab2, cab_b2, yc, pool);
    k_fsum2<<<dim3(64, NB), blk5, 0, stream>>>(O, proj_wt, proj_b, gamma, xn, yc, pool,
                                               ca_w1, ca_b1, ca_w2, ca_b2, x, fsum);
    k_ln<<<dim3(256), blk, 0, stream>>>(fsum, ln_w, ln_b, fs1);
    k_mlp1<<<dim3(64, NB), blk5, 0, stream>>>(fs1, fc1_wt, fc1_b, hbuf);
    k_mlp2<<<dim3(64, NB), blk5, 0, stream>>>(hbuf, fc2_wt, fc2_b, fsum, out);
}

// Round 15
// 244.390 us; speedup vs baseline: 1.0700x; 1.0004x over previous
//
#include <hip/hip_runtime.h>
#include <math.h>

#define NB 4
#define NC 64
#define NC8 8
#define NCC 21
#define NHW 4096
#define NHM 128

typedef __attribute__((ext_vector_type(8))) short bf16x8;
typedef __attribute__((ext_vector_type(4))) float f32x4;

__device__ __forceinline__ float gelu_exact(float x) {
    return 0.5f * x * (1.0f + erff(x * 0.70710678118654752f));
}

__device__ __forceinline__ unsigned short f2bf(float x) {
    union { float f; unsigned u; } u; u.f = x;
    unsigned r = u.u + 0x7fffu + ((u.u >> 16) & 1u);   // RNE
    return (unsigned short)(r >> 16);
}

__device__ __forceinline__ float bf2f(unsigned short v) {
    union { unsigned u; float f; } t; t.u = (unsigned)v << 16; return t.f;
}

// ---------------- weight pack/transpose into [ci][co] layouts; zero pool ----------------
// o: [0) qkv 5120 | [5120) cab1 12096 | [17216) cab2 12096 | [29312) proj 4096
//    [33408) fc1 8192 | [41600) fc2 8192
__global__ void k_wt(const float* __restrict__ qw, const float* __restrict__ kw,
                     const float* __restrict__ vw, const float* __restrict__ c1w,
                     const float* __restrict__ c2w, const float* __restrict__ pw,
                     const float* __restrict__ f1w, const float* __restrict__ f2w,
                     float* __restrict__ o, float* __restrict__ pool) {
    int idx = blockIdx.x * 256 + threadIdx.x;
    if (idx < 256) pool[idx] = 0.f;
    if (idx < 5120) {
        int ci = idx / 80, j = idx - ci * 80;
        float v = j < 8 ? qw[j * 64 + ci] : (j < 16 ? kw[(j - 8) * 64 + ci] : vw[(j - 16) * 64 + ci]);
        o[idx] = v;
    } else if (idx < 17216) {
        int r = idx - 5120; int co = r % 21, q = r / 21; int ci = q / 9, t = q - ci * 9;
        o[idx] = c1w[co * 576 + ci * 9 + t];
    } else if (idx < 29312) {
        int r = idx - 17216; int co = r & 63, q = r >> 6; int ci = q / 9, t = q - ci * 9;
        o[idx] = c2w[co * 189 + ci * 9 + t];
    } else if (idx < 33408) {
        int r = idx - 29312; int co = r & 63, ci = r >> 6;
        o[idx] = pw[co * 64 + ci];
    } else if (idx < 41600) {
        int r = idx - 33408; int m = r & 127, c = r >> 7;
        o[idx] = f1w[m * 64 + c];
    } else if (idx < 49792) {
        int r = idx - 41600; int wo = r & 63, m = r >> 6;
        o[idx] = f2w[wo * 128 + m];
    }
}

// ---------------- LayerNorm over channel dim; 4 threads per pixel; bf16 out ----------------
__global__ __launch_bounds__(256) void k_ln(const float* __restrict__ in, const float* __restrict__ w,
                                            const float* __restrict__ bb, unsigned short* __restrict__ out) {
    __shared__ float r1[4][64], r2[4][64];
    int tid = threadIdx.x;
    int pl = tid & 63, cq = tid >> 6;
    int b = blockIdx.x >> 6;
    int pix = (blockIdx.x & 63) * 64 + pl;
    const float* p = in + (size_t)b * NC * NHW + pix;
    float v[16]; float s = 0.f, ss = 0.f;
    #pragma unroll
    for (int k = 0; k < 16; ++k) {
        float f = p[(size_t)(cq * 16 + k) * NHW];
        v[k] = f; s += f; ss += f * f;
    }
    r1[cq][pl] = s; r2[cq][pl] = ss;
    __syncthreads();
    float S  = r1[0][pl] + r1[1][pl] + r1[2][pl] + r1[3][pl];
    float SS = r2[0][pl] + r2[1][pl] + r2[2][pl] + r2[3][pl];
    float mean = S * (1.0f / 64);
    float rstd = rsqrtf(SS * (1.0f / 64) - mean * mean + 1e-5f);
    unsigned short* q = out + (size_t)b * NC * NHW + pix;
    #pragma unroll
    for (int k = 0; k < 16; ++k) {
        int c = cq * 16 + k;
        q[(size_t)c * NHW] = f2bf((v[k] - mean) * rstd * w[c] + bb[c]);
    }
}

// ---------------- q/k/v 1x1 convs: LDS-tiled full-output GEMM (input read ONCE) ----------------
__global__ __launch_bounds__(512) void k_qkv(const unsigned short* __restrict__ xn,
        const float* __restrict__ wt, const float* __restrict__ qb,
        const float* __restrict__ kb, const float* __restrict__ vb,
        unsigned short* __restrict__ q1, unsigned short* __restrict__ k1,
        unsigned short* __restrict__ v1) {
    __shared__ unsigned short Xs[64][64];
    __shared__ float Ws[64][80];
    int tid = threadIdx.x;
    int pix0 = blockIdx.x * 64, b = blockIdx.y;
    for (int i = tid; i < 1024; i += 512) {
        int c = i >> 4, q4 = i & 15;
        *(ushort4*)&Xs[c][q4 * 4] = *(const ushort4*)(xn + ((size_t)b * NC + c) * NHW + pix0 + q4 * 4);
    }
    for (int i = tid; i < 1280; i += 512)
        *(float4*)&((float*)Ws)[i * 4] = *(const float4*)&wt[i * 4];
    __syncthreads();
    int p2 = (tid & 31) * 2, g = tid >> 5;   // 16 groups x 5 co
    int co0 = g * 5;
    float a0[5], a1[5];
    #pragma unroll
    for (int j = 0; j < 5; ++j) { a0[j] = 0.f; a1[j] = 0.f; }
    for (int ci = 0; ci < 64; ++ci) {
        ushort2 uv = *(const ushort2*)&Xs[ci][p2];
        float fx = bf2f(uv.x), fy = bf2f(uv.y);
        #pragma unroll
        for (int j = 0; j < 5; ++j) {
            float wv = Ws[ci][co0 + j];
            a0[j] = fmaf(fx, wv, a0[j]);
            a1[j] = fmaf(fy, wv, a1[j]);
        }
    }
    #pragma unroll
    for (int j = 0; j < 5; ++j) {
        int co = co0 + j;
        float bsv; unsigned short* dst;
        if (co < 8)       { bsv = qb[co];      dst = q1 + ((size_t)b * NC8 + co) * NHW + pix0 + p2; }
        else if (co < 16) { bsv = kb[co - 8];  dst = k1 + ((size_t)b * NC8 + co - 8) * NHW + pix0 + p2; }
        else              { bsv = vb[co - 16]; dst = v1 + ((size_t)b * NC + co - 16) * NHW + pix0 + p2; }
        ushort2 o = { f2bf(a0[j] + bsv), f2bf(a1[j] + bsv) };
        *(ushort2*)dst = o;
    }
}

// ---------------- depthwise 3x3, q+k merged: bf16 in, bf16 out, (b,pix,8) layout ----------------
__global__ void k_dw3x3_qk(const unsigned short* __restrict__ q1, const unsigned short* __restrict__ k1,
                           const float* __restrict__ w, const float* __restrict__ bias,
                           unsigned short* __restrict__ qdb, unsigned short* __restrict__ kdb) {
    int pix = blockIdx.x * blockDim.x + threadIdx.x;
    int cy = blockIdx.y, b = blockIdx.z;
    int c = cy & 7;
    const unsigned short* ip = (cy < 8 ? q1 : k1) + ((size_t)b * NC8 + c) * NHW;
    unsigned short* outT = (cy < 8 ? qdb : kdb);
    int y = pix >> 6, x = pix & 63;
    const float* wp = w + c * 9;
    float acc = bias[c];
    #pragma unroll
    for (int dy = -1; dy <= 1; ++dy) {
        int yy = y + dy; if (yy < 0 || yy > 63) continue;
        #pragma unroll
        for (int dx = -1; dx <= 1; ++dx) {
            int xx = x + dx; if (xx < 0 || xx > 63) continue;
            acc += wp[(dy + 1) * 3 + (dx + 1)] * bf2f(ip[yy * 64 + xx]);
        }
    }
    outT[((size_t)b * NHW + pix) * NC8 + c] = f2bf(acc);
}

// ---------------- depthwise 3x3, v path: bf16 in/out, chunked layout V8[b][pix>>3][c][pix&7] ----------------
__global__ void k_dw3x3_v(const unsigned short* __restrict__ in, const float* __restrict__ w,
                          const float* __restrict__ bias, unsigned short* __restrict__ v8) {
    int pix = blockIdx.x * blockDim.x + threadIdx.x;
    int c = blockIdx.y, b = blockIdx.z;
    int y = pix >> 6, x = pix & 63;
    const unsigned short* ip = in + ((size_t)b * NC + c) * NHW;
    const float* wp = w + c * 9;
    float acc = bias[c];
    #pragma unroll
    for (int dy = -1; dy <= 1; ++dy) {
        int yy = y + dy; if (yy < 0 || yy > 63) continue;
        #pragma unroll
        for (int dx = -1; dx <= 1; ++dx) {
            int xx = x + dx; if (xx < 0 || xx > 63) continue;
            acc += wp[(dy + 1) * 3 + (dx + 1)] * bf2f(ip[yy * 64 + xx]);
        }
    }
    v8[(((size_t)b * 512 + (pix >> 3)) * NC + c) * 8 + (pix & 7)] = f2bf(acc);
}

// ---------------- flash attention: 8 waves/block, i-tile x2 in-wave, chunked-V, LDS union ----------------
__global__ __launch_bounds__(512) void k_flash(const unsigned short* __restrict__ qdb,
                                               const unsigned short* __restrict__ kdb,
                                               const unsigned short* __restrict__ v8,
                                               unsigned short* __restrict__ O) {
    __shared__ __align__(16) char smem[35840];  // max(Pl 18432, Ocmb 34816 + Lw 1024)
    int tid = threadIdx.x;
    int w = tid >> 6, lane = tid & 63;
    int g = lane >> 4, il = lane & 15;
    int i0 = blockIdx.x * 32, b = blockIdx.y;

    unsigned short (*P)[72] = (unsigned short (*)[72])(smem + w * 2304);

    bf16x8 qb0 = (bf16x8)(short)0, qb1 = (bf16x8)(short)0;
    if (g == 0) {
        qb0 = *(const bf16x8*)(qdb + (size_t)(b * NHW + i0 + il) * NC8);
        qb1 = *(const bf16x8*)(qdb + (size_t)(b * NHW + i0 + 16 + il) * NC8);
    }

    f32x4 acc0[4], acc1[4];
    #pragma unroll
    for (int ct = 0; ct < 4; ++ct) {
        acc0[ct] = (f32x4){0.f, 0.f, 0.f, 0.f};
        acc1[ct] = (f32x4){0.f, 0.f, 0.f, 0.f};
    }
    float La0 = 0.f, La1 = 0.f;

    bf16x8 kn[4];
    #pragma unroll
    for (int t = 0; t < 4; ++t) {
        kn[t] = (bf16x8)(short)0;
        if (g == 0) kn[t] = *(const bf16x8*)(kdb + (size_t)(b * NHW + w * 512 + 16 * t + il) * NC8);
    }

    for (int jt = 0; jt < 8; ++jt) {
        int j0 = w * 512 + jt * 64;
        int ch0 = b * 512 + (j0 >> 3);
        bf16x8 va[2][4];
        #pragma unroll
        for (int kc = 0; kc < 2; ++kc)
            #pragma unroll
            for (int ct = 0; ct < 4; ++ct)
                va[kc][ct] = *(const bf16x8*)(v8 +
                    ((size_t)(ch0 + kc * 4 + g) * NC + ct * 16 + il) * 8);
        bf16x8 ka[4];
        #pragma unroll
        for (int t = 0; t < 4; ++t) ka[t] = kn[t];
        if (jt < 7) {
            #pragma unroll
            for (int t = 0; t < 4; ++t) {
                kn[t] = (bf16x8)(short)0;
                if (g == 0) kn[t] = *(const bf16x8*)(kdb + (size_t)(b * NHW + j0 + 64 + 16 * t + il) * NC8);
            }
        }
        // ---- strip 0 ----
        #pragma unroll
        for (int t = 0; t < 4; ++t) {
            f32x4 sv = __builtin_amdgcn_mfma_f32_16x16x32_bf16(ka[t], qb0, (f32x4){0.f, 0.f, 0.f, 0.f}, 0, 0, 0);
            float p0 = __expf(sv[0]), p1 = __expf(sv[1]);
            float p2 = __expf(sv[2]), p3 = __expf(sv[3]);
            La0 += (p0 + p1) + (p2 + p3);
            ushort4 pk;
            pk.x = f2bf(p0); pk.y = f2bf(p1); pk.z = f2bf(p2); pk.w = f2bf(p3);
            *(ushort4*)&P[il][16 * t + 4 * g] = pk;
        }
        #pragma unroll
        for (int kc = 0; kc < 2; ++kc) {
            bf16x8 pb = *(const bf16x8*)&P[il][kc * 32 + 8 * g];
            #pragma unroll
            for (int ct = 0; ct < 4; ++ct)
                acc0[ct] = __builtin_amdgcn_mfma_f32_16x16x32_bf16(va[kc][ct], pb, acc0[ct], 0, 0, 0);
        }
        // ---- strip 1 (reuse P, same ka/va) ----
        #pragma unroll
        for (int t = 0; t < 4; ++t) {
            f32x4 sv = __builtin_amdgcn_mfma_f32_16x16x32_bf16(ka[t], qb1, (f32x4){0.f, 0.f, 0.f, 0.f}, 0, 0, 0);
            float p0 = __expf(sv[0]), p1 = __expf(sv[1]);
            float p2 = __expf(sv[2]), p3 = __expf(sv[3]);
            La1 += (p0 + p1) + (p2 + p3);
            ushort4 pk;
            pk.x = f2bf(p0); pk.y = f2bf(p1); pk.z = f2bf(p2); pk.w = f2bf(p3);
            *(ushort4*)&P[il][16 * t + 4 * g] = pk;
        }
        #pragma unroll
        for (int kc = 0; kc < 2; ++kc) {
            bf16x8 pb = *(const bf16x8*)&P[il][kc * 32 + 8 * g];
            #pragma unroll
            for (int ct = 0; ct < 4; ++ct)
                acc1[ct] = __builtin_amdgcn_mfma_f32_16x16x32_bf16(va[kc][ct], pb, acc1[ct], 0, 0, 0);
        }
    }
    La0 += __shfl_xor(La0, 16, 64); La0 += __shfl_xor(La0, 32, 64);
    La1 += __shfl_xor(La1, 16, 64); La1 += __shfl_xor(La1, 32, 64);

    __syncthreads();
    unsigned short* Ocm = (unsigned short*)smem;           // [16][64*17] bf16
    float* Lw = (float*)(smem + 34816);                    // [16][16]
    #pragma unroll
    for (int ct = 0; ct < 4; ++ct)
        #pragma unroll
        for (int e = 0; e < 4; ++e) {
            int c = ct * 16 + 4 * g + e;
            Ocm[(w * 2 + 0) * 1088 + c * 17 + il] = f2bf(acc0[ct][e]);
            Ocm[(w * 2 + 1) * 1088 + c * 17 + il] = f2bf(acc1[ct][e]);
        }
    if (lane < 16) {
        Lw[(w * 2 + 0) * 16 + il] = La0;
        Lw[(w * 2 + 1) * 16 + il] = La1;
    }
    __syncthreads();

    int st = tid >> 8, rem = tid & 255;
    int ic = rem & 15, ch = rem >> 4;
    float l = 0.f;
    #pragma unroll
    for (int w2 = 0; w2 < 8; ++w2) l += Lw[(w2 * 2 + st) * 16 + ic];
    float rl = 1.0f / l;
    #pragma unroll
    for (int cc = 0; cc < 4; ++cc) {
        int c = cc * 16 + ch;
        float o = 0.f;
        #pragma unroll
        for (int w2 = 0; w2 < 8; ++w2) o += bf2f(Ocm[(w2 * 2 + st) * 1088 + c * 17 + ic]);
        O[(size_t)(b * NC + c) * NHW + i0 + st * 16 + ic] = f2bf(o * rl);
    }
}

// ---------------- CAB conv1 3x3 (64->21), bf16 in, K-split x8, LDS weights, 2 pix ----------------
__global__ __launch_bounds__(256) void k_cab1_p(const unsigned short* __restrict__ xn,
        const float* __restrict__ wt, float* __restrict__ part) {
    __shared__ float wl[72][24];
    int tid = threadIdx.x;
    int s = blockIdx.y, b = blockIdx.z;
    for (int idx = tid; idx < 432; idx += 256) {
        int lt = idx / 6, j4 = idx % 6;
        int ci = s * 8 + lt / 9, t = lt % 9;
        float4 v;
        v.x = (j4 * 4 + 0 < 21) ? wt[(ci * 9 + t) * 21 + j4 * 4 + 0] : 0.f;
        v.y = (j4 * 4 + 1 < 21) ? wt[(ci * 9 + t) * 21 + j4 * 4 + 1] : 0.f;
        v.z = (j4 * 4 + 2 < 21) ? wt[(ci * 9 + t) * 21 + j4 * 4 + 2] : 0.f;
        v.w = (j4 * 4 + 3 < 21) ? wt[(ci * 9 + t) * 21 + j4 * 4 + 3] : 0.f;
        *(float4*)&wl[lt][j4 * 4] = v;
    }
    __syncthreads();
    int pix = (blockIdx.x * 256 + tid) * 2;
    int y = pix >> 6, x0 = pix & 63;
    float a0[21], a1[21];
    #pragma unroll
    for (int co = 0; co < 21; ++co) { a0[co] = 0.f; a1[co] = 0.f; }
    const unsigned short* ip0 = xn + (size_t)b * NC * NHW;
    for (int cc = 0; cc < 8; ++cc) {
        const unsigned short* ip = ip0 + (size_t)(s * 8 + cc) * NHW;
        #pragma unroll
        for (int dy = -1; dy <= 1; ++dy) {
            int yy = y + dy;
            bool yok = (unsigned)yy < 64u;
            #pragma unroll
            for (int dx = -1; dx <= 1; ++dx) {
                int xx0 = x0 + dx, xx1 = x0 + 1 + dx;
                float v0 = (yok && (unsigned)xx0 < 64u) ? bf2f(ip[yy * 64 + xx0]) : 0.f;
                float v1 = (yok && (unsigned)xx1 < 64u) ? bf2f(ip[yy * 64 + xx1]) : 0.f;
                const float* wr = wl[cc * 9 + (dy + 1) * 3 + (dx + 1)];
                float wv[24];
                *(float4*)&wv[0]  = *(const float4*)&wr[0];
                *(float4*)&wv[4]  = *(const float4*)&wr[4];
                *(float4*)&wv[8]  = *(const float4*)&wr[8];
                *(float4*)&wv[12] = *(const float4*)&wr[12];
                *(float4*)&wv[16] = *(const float4*)&wr[16];
                *(float4*)&wv[20] = *(const float4*)&wr[20];
                #pragma unroll
                for (int co = 0; co < 21; ++co) {
                    a0[co] = fmaf(v0, wv[co], a0[co]);
                    a1[co] = fmaf(v1, wv[co], a1[co]);
                }
            }
        }
    }
    size_t ob = ((size_t)(s * NB + b) * NCC) * NHW + pix;
    #pragma unroll
    for (int co = 0; co < 21; ++co) {
        float2 o = { a0[co], a1[co] };
        *(float2*)&part[ob + (size_t)co * NHW] = o;
    }
}

__global__ void k_cab1_c(const float* __restrict__ part, const float* __restrict__ bias,
                         float* __restrict__ y1) {
    int pix = blockIdx.x * 256 + threadIdx.x;
    int co = blockIdx.y, b = blockIdx.z;
    float s = bias[co];
    #pragma unroll
    for (int sp = 0; sp < 8; ++sp)
        s += part[((size_t)(sp * NB + b) * NCC + co) * NHW + pix];
    y1[((size_t)b * NCC + co) * NHW + pix] = gelu_exact(s);
}

// ---------------- CAB conv2 3x3 (21->64), K-split x7 * co-split x2, LDS weights, 2 pix ----------------
__global__ __launch_bounds__(256) void k_cab2_p(const float* __restrict__ y1,
        const float* __restrict__ wt, float* __restrict__ part) {
    __shared__ float wl[27][32];
    int tid = threadIdx.x;
    int s = blockIdx.y >> 1, co0 = (blockIdx.y & 1) * 32, b = blockIdx.z;
    for (int idx = tid; idx < 216; idx += 256) {
        int lt = idx >> 3, j4 = idx & 7;
        int ci = s * 3 + lt / 9, t = lt % 9;
        *(float4*)&wl[lt][j4 * 4] = *(const float4*)&wt[(ci * 9 + t) * 64 + co0 + j4 * 4];
    }
    __syncthreads();
    int pix = (blockIdx.x * 256 + tid) * 2;
    int y = pix >> 6, x0 = pix & 63;
    float a0[32], a1[32];
    #pragma unroll
    for (int co = 0; co < 32; ++co) { a0[co] = 0.f; a1[co] = 0.f; }
    const float* ip0 = y1 + (size_t)b * NCC * NHW;
    for (int cc = 0; cc < 3; ++cc) {
        const float* ip = ip0 + (size_t)(s * 3 + cc) * NHW;
        #pragma unroll
        for (int dy = -1; dy <= 1; ++dy) {
            int yy = y + dy;
            bool yok = (unsigned)yy < 64u;
            #pragma unroll
            for (int dx = -1; dx <= 1; ++dx) {
                int xx0 = x0 + dx, xx1 = x0 + 1 + dx;
                float v0 = (yok && (unsigned)xx0 < 64u) ? ip[yy * 64 + xx0] : 0.f;
                float v1 = (yok && (unsigned)xx1 < 64u) ? ip[yy * 64 + xx1] : 0.f;
                const float* wr = wl[cc * 9 + (dy + 1) * 3 + (dx + 1)];
                float wv[32];
                #pragma unroll
                for (int h = 0; h < 8; ++h)
                    *(float4*)&wv[h * 4] = *(const float4*)&wr[h * 4];
                #pragma unroll
                for (int co = 0; co < 32; ++co) {
                    a0[co] = fmaf(v0, wv[co], a0[co]);
                    a1[co] = fmaf(v1, wv[co], a1[co]);
                }
            }
        }
    }
    size_t ob = ((size_t)(s * NB + b) * NC + co0) * NHW + pix;
    #pragma unroll
    for (int co = 0; co < 32; ++co) {
        float2 o = { a0[co], a1[co] };
        *(float2*)&part[ob + (size_t)co * NHW] = o;
    }
}

// ---------------- combine cab2 partials + fused global-avg-pool; yc bf16 out ----------------
__global__ void k_cab2_c(const float* __restrict__ part, const float* __restrict__ bias,
                         unsigned short* __restrict__ yc, float* __restrict__ pool) {
    __shared__ float red[256];
    int tid = threadIdx.x;
    int pix = blockIdx.x * 256 + tid;
    int co = blockIdx.y, b = blockIdx.z;
    float s = bias[co];
    #pragma unroll
    for (int sp = 0; sp < 7; ++sp)
        s += part[((size_t)(sp * NB + b) * NC + co) * NHW + pix];
    yc[((size_t)b * NC + co) * NHW + pix] = f2bf(s);
    red[tid] = s;
    __syncthreads();
    for (int st = 128; st > 0; st >>= 1) {
        if (tid < st) red[tid] += red[tid + st];
        __syncthreads();
    }
    if (tid == 0) atomicAdd(&pool[b * NC + co], red[0]);
}

// ---------------- proj + CA + residuals + fused LN2: LDS-tiled full-output ----------------
// Block = 512 thr, 64-pixel tile, all 64 co. Os 8KB + Ws 16KB + Fs 16.5KB.
// Outputs: fsum (bf16, residual for mlp2) and fs1 (bf16, LN2 of fsum) in one pass.
__global__ __launch_bounds__(512) void k_fsum2(const unsigned short* __restrict__ O,
        const float* __restrict__ pwt, const float* __restrict__ pb,
        const float* __restrict__ gamma, const unsigned short* __restrict__ xn,
        const unsigned short* __restrict__ yc, const float* __restrict__ pool,
        const float* __restrict__ cw1, const float* __restrict__ cb1,
        const float* __restrict__ cw2, const float* __restrict__ cb2,
        const float* __restrict__ x, const float* __restrict__ lnw,
        const float* __restrict__ lnb, unsigned short* __restrict__ fsum,
        unsigned short* __restrict__ fs1) {
    __shared__ unsigned short Os[64][64];
    __shared__ float Ws[64][64];
    __shared__ float Fs[64][66];
    __shared__ float mean_s[64], rstd_s[64];
    int tid = threadIdx.x;
    int pix0 = blockIdx.x * 64, b = blockIdx.y;
    for (int i = tid; i < 1024; i += 512) {
        int c = i >> 4, q4 = i & 15;
        *(ushort4*)&Os[c][q4 * 4] = *(const ushort4*)(O + ((size_t)b * NC + c) * NHW + pix0 + q4 * 4);
    }
    for (int i = tid; i < 1024; i += 512)
        *(float4*)&((float*)Ws)[i * 4] = *(const float4*)&pwt[i * 4];
    __syncthreads();
    // channel attention (uniform per block)
    float h0 = cb1[0], h1 = cb1[1];
    for (int ci = 0; ci < NC; ++ci) {
        float pv = pool[b * NC + ci] * (1.0f / NHW);
        h0 += cw1[ci] * pv;
        h1 += cw1[NC + ci] * pv;
    }
    h0 = fmaxf(h0, 0.f); h1 = fmaxf(h1, 0.f);
    int p2 = (tid & 31) * 2, g = tid >> 5;   // 16 groups x 4 co
    int co0 = g * 4;
    float scv[4];
    #pragma unroll
    for (int j = 0; j < 4; ++j) {
        int c = co0 + j;
        float z = cw2[c * 2] * h0 + cw2[c * 2 + 1] * h1 + cb2[c];
        scv[j] = 1.0f / (1.0f + __expf(-z));
    }
    float a0[4], a1[4];
    #pragma unroll
    for (int j = 0; j < 4; ++j) { a0[j] = 0.f; a1[j] = 0.f; }
    for (int ci = 0; ci < 64; ++ci) {
        ushort2 uv = *(const ushort2*)&Os[ci][p2];
        float ox = bf2f(uv.x), oy = bf2f(uv.y);
        float wv[4];
        *(float4*)wv = *(const float4*)&Ws[ci][co0];
        #pragma unroll
        for (int j = 0; j < 4; ++j) {
            a0[j] = fmaf(ox, wv[j], a0[j]);
            a1[j] = fmaf(oy, wv[j], a1[j]);
        }
    }
    float gg = gamma[0];
    size_t base = (size_t)b * NC * NHW + pix0 + p2;
    float f0[4], f1[4];
    #pragma unroll
    for (int j = 0; j < 4; ++j) {
        int c = co0 + j;
        size_t n = base + (size_t)c * NHW;
        float pbv = pb[c];
        ushort2 xnu = *(const ushort2*)&xn[n];
        ushort2 ycu = *(const ushort2*)&yc[n];
        float2 xv  = *(const float2*)&x[n];
        f0[j] = gg * (a0[j] + pbv) + bf2f(xnu.x) + bf2f(ycu.x) * scv[j] + xv.x;
        f1[j] = gg * (a1[j] + pbv) + bf2f(xnu.y) + bf2f(ycu.y) * scv[j] + xv.y;
        ushort2 o = { f2bf(f0[j]), f2bf(f1[j]) };
        *(ushort2*)&fsum[n] = o;
        Fs[c][p2] = f0[j]; Fs[c][p2 + 1] = f1[j];
    }
    __syncthreads();
    if (tid < 64) {
        float s = 0.f, ss = 0.f;
        for (int c = 0; c < 64; ++c) { float v = Fs[c][tid]; s += v; ss += v * v; }
        float mean = s * (1.0f / 64);
        mean_s[tid] = mean;
        rstd_s[tid] = rsqrtf(ss * (1.0f / 64) - mean * mean + 1e-5f);
    }
    __syncthreads();
    float m0 = mean_s[p2], r0 = rstd_s[p2];
    float m1 = mean_s[p2 + 1], r1 = rstd_s[p2 + 1];
    #pragma unroll
    for (int j = 0; j < 4; ++j) {
        int c = co0 + j;
        size_t n = base + (size_t)c * NHW;
        float lw = lnw[c], lb = lnb[c];
        ushort2 o = { f2bf((f0[j] - m0) * r0 * lw + lb),
                      f2bf((f1[j] - m1) * r1 * lw + lb) };
        *(ushort2*)&fs1[n] = o;
    }
}

// ---------------- MLP fc1 + gelu: LDS-tiled full-output (fs1 read ONCE) ----------------
__global__ __launch_bounds__(512) void k_mlp1(const unsigned short* __restrict__ fs1,
        const float* __restrict__ wt, const float* __restrict__ bias,
        unsigned short* __restrict__ h) {
    __shared__ unsigned short Fs[64][64];
    __shared__ float Ws[64][128];
    int tid = threadIdx.x;
    int pix0 = blockIdx.x * 64, b = blockIdx.y;
    for (int i = tid; i < 1024; i += 512) {
        int c = i >> 4, q4 = i & 15;
        *(ushort4*)&Fs[c][q4 * 4] = *(const ushort4*)(fs1 + ((size_t)b * NC + c) * NHW + pix0 + q4 * 4);
    }
    for (int i = tid; i < 2048; i += 512)
        *(float4*)&((float*)Ws)[i * 4] = *(const float4*)&wt[i * 4];
    __syncthreads();
    int p2 = (tid & 31) * 2, g = tid >> 5;   // 16 groups x 8 m
    int m0 = g * 8;
    float a0[8], a1[8];
    #pragma unroll
    for (int j = 0; j < 8; ++j) { float bv = bias[m0 + j]; a0[j] = bv; a1[j] = bv; }
    for (int c = 0; c < 64; ++c) {
        ushort2 uv = *(const ushort2*)&Fs[c][p2];
        float vx = bf2f(uv.x), vy = bf2f(uv.y);
        float wv[8];
        *(float4*)&wv[0] = *(const float4*)&Ws[c][m0];
        *(float4*)&wv[4] = *(const float4*)&Ws[c][m0 + 4];
        #pragma unroll
        for (int j = 0; j < 8; ++j) {
            a0[j] = fmaf(vx, wv[j], a0[j]);
            a1[j] = fmaf(vy, wv[j], a1[j]);
        }
    }
    unsigned short* hp = h + (size_t)b * NHM * NHW + pix0 + p2;
    #pragma unroll
    for (int j = 0; j < 8; ++j) {
        ushort2 o = { f2bf(gelu_exact(a0[j])), f2bf(gelu_exact(a1[j])) };
        *(ushort2*)(hp + (size_t)(m0 + j) * NHW) = o;
    }
}

// ---------------- MLP fc2 + raw-view permutation + residual: LDS-tiled (hbuf read ONCE) ----------------
__global__ __launch_bounds__(512) void k_mlp2(const unsigned short* __restrict__ h,
        const float* __restrict__ wt, const float* __restrict__ bias,
        const unsigned short* __restrict__ fs, float* __restrict__ out) {
    __shared__ unsigned short Hs[128][64];
    __shared__ float Ws[128][64];
    int tid = threadIdx.x;
    int pix0 = blockIdx.x * 64, b = blockIdx.y;
    for (int i = tid; i < 2048; i += 512) {
        int m = i >> 4, q4 = i & 15;
        *(ushort4*)&Hs[m][q4 * 4] = *(const ushort4*)(h + ((size_t)b * NHM + m) * NHW + pix0 + q4 * 4);
    }
    for (int i = tid; i < 2048; i += 512)
        *(float4*)&((float*)Ws)[i * 4] = *(const float4*)&wt[i * 4];
    __syncthreads();
    int p2 = (tid & 31) * 2, g = tid >> 5;   // 16 groups x 4 wo
    int wo0 = g * 4;
    float a0[4], a1[4];
    #pragma unroll
    for (int j = 0; j < 4; ++j) { float bv = bias[wo0 + j]; a0[j] = bv; a1[j] = bv; }
    for (int m = 0; m < 128; ++m) {
        ushort2 uv = *(const ushort2*)&Hs[m][p2];
        float vx = bf2f(uv.x), vy = bf2f(uv.y);
        float wv[4];
        *(float4*)wv = *(const float4*)&Ws[m][wo0];
        #pragma unroll
        for (int j = 0; j < 4; ++j) {
            a0[j] = fmaf(vx, wv[j], a0[j]);
            a1[j] = fmaf(vy, wv[j], a1[j]);
        }
    }
    // out flat index: (b*4096+pix)*64 + wo; fsum (bf16, NCHW) flat aliases same offsets
    size_t ob0 = ((size_t)b * NHW + pix0 + p2) * 64 + wo0;
    ushort4 r0 = *(const ushort4*)&fs[ob0];
    ushort4 r1 = *(const ushort4*)&fs[ob0 + 64];
    float4 w0, w1;
    w0.x = a0[0] + bf2f(r0.x); w0.y = a0[1] + bf2f(r0.y);
    w0.z = a0[2] + bf2f(r0.z); w0.w = a0[3] + bf2f(r0.w);
    w1.x = a1[0] + bf2f(r1.x); w1.y = a1[1] + bf2f(r1.y);
    w1.z = a1[2] + bf2f(r1.z); w1.w = a1[3] + bf2f(r1.w);
    *(float4*)&out[ob0] = w0;
    *(float4*)&out[ob0 + 64] = w1;
}

extern "C" void kernel_launch(void* const* d_in, const int* in_sizes, int n_in,
                              void* d_out, int out_size, void* d_ws, size_t ws_size,
                              hipStream_t stream) {
    const float* x        = (const float*)d_in[0];
    const float* ln_w     = (const float*)d_in[1];
    const float* ln_b     = (const float*)d_in[2];
    const float* q_w      = (const float*)d_in[3];
    const float* q_b      = (const float*)d_in[4];
    const float* k_w      = (const float*)d_in[5];
    const float* k_b      = (const float*)d_in[6];
    const float* v_w      = (const float*)d_in[7];
    const float* v_b      = (const float*)d_in[8];
    const float* qkdw_w   = (const float*)d_in[9];
    const float* qkdw_b   = (const float*)d_in[10];
    const float* vdw_w    = (const float*)d_in[11];
    const float* vdw_b    = (const float*)d_in[12];
    const float* proj_w   = (const float*)d_in[13];
    const float* proj_b   = (const float*)d_in[14];
    const float* gamma    = (const float*)d_in[15];
    const float* cab_w1   = (const float*)d_in[16];
    const float* cab_b1   = (const float*)d_in[17];
    const float* cab_w2   = (const float*)d_in[18];
    const float* cab_b2   = (const float*)d_in[19];
    const float* ca_w1    = (const float*)d_in[20];
    const float* ca_b1    = (const float*)d_in[21];
    const float* ca_w2    = (const float*)d_in[22];
    const float* ca_b2    = (const float*)d_in[23];
    const float* fc1_w    = (const float*)d_in[24];
    const float* fc1_b    = (const float*)d_in[25];
    const float* fc2_w    = (const float*)d_in[26];
    const float* fc2_b    = (const float*)d_in[27];
    float* out = (float*)d_out;

    char* ws = (char*)d_ws;
    size_t off = 0;
    auto alloc = [&](size_t bytes) { void* p = ws + off; off += (bytes + 255) & ~(size_t)255; return p; };
    unsigned short* xn = (unsigned short*)alloc((size_t)NB * NC * NHW * 2);
    unsigned short* q1 = (unsigned short*)alloc((size_t)NB * NC8 * NHW * 2);
    unsigned short* k1 = (unsigned short*)alloc((size_t)NB * NC8 * NHW * 2);
    unsigned short* v1 = (unsigned short*)alloc((size_t)NB * NC * NHW * 2);
    unsigned short* qdb = (unsigned short*)alloc((size_t)NB * NHW * NC8 * 2);
    unsigned short* kdb = (unsigned short*)alloc((size_t)NB * NHW * NC8 * 2);
    unsigned short* vdb = (unsigned short*)alloc((size_t)NB * NC * NHW * 2);
    unsigned short* O   = (unsigned short*)alloc((size_t)NB * NC * NHW * 2);
    float* y1    = (float*)alloc((size_t)NB * NCC * NHW * 4);
    unsigned short* yc = (unsigned short*)alloc((size_t)NB * NC * NHW * 2);
    float* pool  = (float*)alloc(256 * 4);
    unsigned short* fsum = (unsigned short*)alloc((size_t)NB * NC * NHW * 2);
    unsigned short* fs1 = (unsigned short*)alloc((size_t)NB * NC * NHW * 2);
    unsigned short* hbuf = (unsigned short*)alloc((size_t)NB * NHM * NHW * 2);
    float* pcab1 = (float*)alloc((size_t)8 * NB * NCC * NHW * 4);
    float* pcab2 = (float*)alloc((size_t)7 * NB * NC * NHW * 4);
    float* wpack = (float*)alloc(49792 * 4);

    float* qkv_wt  = wpack;
    float* cab1_wt = wpack + 5120;
    float* cab2_wt = wpack + 17216;
    float* proj_wt = wpack + 29312;
    float* fc1_wt  = wpack + 33408;
    float* fc2_wt  = wpack + 41600;

    dim3 blk(256);
    dim3 blk5(512);

    k_wt<<<dim3(195), blk, 0, stream>>>(q_w, k_w, v_w, cab_w1, cab_w2, proj_w, fc1_w, fc2_w, wpack, pool);
    k_ln<<<dim3(256), blk, 0, stream>>>(x, ln_w, ln_b, xn);
    k_qkv<<<dim3(64, NB), blk5, 0, stream>>>(xn, qkv_wt, q_b, k_b, v_b, q1, k1, v1);
    k_dw3x3_qk<<<dim3(16, 16, NB), blk, 0, stream>>>(q1, k1, qkdw_w, qkdw_b, qdb, kdb);
    k_dw3x3_v<<<dim3(16, NC, NB), blk, 0, stream>>>(v1, vdw_w, vdw_b, vdb);
    k_flash<<<dim3(128, NB), blk5, 0, stream>>>(qdb, kdb, vdb, O);
    k_cab1_p<<<dim3(8, 8, NB), blk, 0, stream>>>(xn, cab1_wt, pcab1);
    k_cab1_c<<<dim3(16, NCC, NB), blk, 0, stream>>>(pcab1, cab_b1, y1);
    k_cab2_p<<<dim3(8, 14, NB), blk, 0, stream>>>(y1, cab2_wt, pcab2);
    k_cab2_c<<<dim3(16, NC, NB), blk, 0, stream>>>(pcab2, cab_b2, yc, pool);
    k_fsum2<<<dim3(64, NB), blk5, 0, stream>>>(O, proj_wt, proj_b, gamma, xn, yc, pool,
                                               ca_w1, ca_b1, ca_w2, ca_b2, x, ln_w, ln_b,
                                               fsum, fs1);
    k_mlp1<<<dim3(64, NB), blk5, 0, stream>>>(fs1, fc1_wt, fc1_b, hbuf);
    k_mlp2<<<dim3(64, NB), blk5, 0, stream>>>(hbuf, fc2_wt, fc2_b, fsum, out);
}